// Round 16
// baseline (424.227 us; speedup 1.0000x reference)
//
#include <hip/hip_runtime.h>
#include <hip/hip_bf16.h>
#include <math.h>

#define Bn 32
#define Tn 1024
#define DIMn 512
#define Hn 8
#define HDn 64
#define HIDn 2048
#define Mn 32768

using short8 = __attribute__((ext_vector_type(8))) short;
using half8  = __attribute__((ext_vector_type(8))) _Float16;
using f32x4  = __attribute__((ext_vector_type(4))) float;
typedef unsigned short u16;
typedef unsigned int   u32;

__device__ __forceinline__ u16 f2h(float x) {
  _Float16 h = (_Float16)x;
  return __builtin_bit_cast(u16, h);
}
__device__ __forceinline__ float h2f(u16 u) {
  return (float)__builtin_bit_cast(_Float16, u);
}
__device__ __forceinline__ u32 pack2h(float a, float b) {
  return (u32)f2h(a) | ((u32)f2h(b) << 16);
}
__device__ __forceinline__ void gld16(const void* g, void* l) {
  __builtin_amdgcn_global_load_lds((const __attribute__((address_space(1))) u32*)g,
                                   (__attribute__((address_space(3))) u32*)l, 16, 0, 0);
}
__device__ __forceinline__ float wredsum(float v) {
  #pragma unroll
  for (int d = 1; d < 64; d <<= 1) v += __shfl_xor(v, d, 64);
  return v;
}
__device__ __forceinline__ void hard_barrier() {
  asm volatile("" ::: "memory");
  __builtin_amdgcn_s_barrier();
  asm volatile("" ::: "memory");
}
// Abramowitz-Stegun 7.1.26 erf (|err|<1.5e-7) -> exact GELU at f16 resolution
__device__ __forceinline__ float fast_gelu(float v) {
  const float ax = fabsf(v) * 0.70710678118654752f;
  const float t = 1.0f / (1.0f + 0.3275911f * ax);
  const float p = ((((1.061405429f * t - 1.453152027f) * t) + 1.421413741f) * t - 0.284496736f) * t + 0.254829592f;
  const float y = 1.0f - p * t * __expf(-ax * ax);
  const float erfv = (v >= 0.f) ? y : -y;
  return 0.5f * v * (1.0f + erfv);
}

// ---------------- column sums of x ----------------
__global__ __launch_bounds__(256) void colsum1(const float* __restrict__ x, float* __restrict__ part) {
  const int b = blockIdx.x, t = threadIdx.x;
  const float* p = x + (size_t)b * 128 * DIMn;
  float a0 = 0.f, a1 = 0.f;
  for (int r = 0; r < 128; ++r) {
    a0 += p[r * DIMn + t];
    a1 += p[r * DIMn + t + 256];
  }
  part[b * DIMn + t] = a0;
  part[b * DIMn + t + 256] = a1;
}

__global__ __launch_bounds__(256) void colsum2(const float* __restrict__ part, float* __restrict__ xs) {
  const int c = blockIdx.x * 256 + threadIdx.x;
  float a = 0.f;
  for (int b = 0; b < 256; ++b) a += part[b * DIMn + c];
  xs[c] = a;
}

// SVp[h][f] = XS . Wqkv[:,1024+h*64+f] + 32768*bqkv[...]   (grid 8, 256 thr)
__global__ __launch_bounds__(256) void sv_k(const float* __restrict__ xs, const float* __restrict__ Wqkv,
                                            const float* __restrict__ bqkv, float* __restrict__ SVp) {
  __shared__ float xsh[512];
  __shared__ float red[4][64];
  const int h = blockIdx.x, q = threadIdx.x >> 6, f = threadIdx.x & 63;
  xsh[threadIdx.x] = xs[threadIdx.x];
  xsh[threadIdx.x + 256] = xs[threadIdx.x + 256];
  __syncthreads();
  const int colb = 2 * DIMn + h * HDn + f;
  float acc = 0.f;
  for (int i = q * 128; i < q * 128 + 128; ++i) acc += xsh[i] * Wqkv[(size_t)i * 1536 + colb];
  red[q][f] = acc;
  __syncthreads();
  if (q == 0)
    SVp[h * 64 + f] = red[0][f] + red[1][f] + red[2][f] + red[3][f] + 32768.0f * bqkv[colb];
}

// attnc[j] = bsa[j] + sum_i SV[i&63]*Wsa[i][j]   (grid 8, 256 thr)
__global__ __launch_bounds__(256) void attnc2_k(const float* __restrict__ SVp, const float* __restrict__ Wsa,
                                                const float* __restrict__ bsa, float* __restrict__ attnc) {
  __shared__ float SVs[64];
  __shared__ float red[4][64];
  const int q = threadIdx.x >> 6, jj = threadIdx.x & 63;
  if (threadIdx.x < 64) {
    float s = 0.f;
    #pragma unroll
    for (int h = 0; h < 8; ++h) s += SVp[h * 64 + threadIdx.x];
    SVs[threadIdx.x] = s;
  }
  __syncthreads();
  const int j = blockIdx.x * 64 + jj;
  float acc = 0.f;
  for (int i = q * 128; i < q * 128 + 128; ++i) acc += SVs[i & 63] * Wsa[(size_t)i * DIMn + j];
  red[q][jj] = acc;
  __syncthreads();
  if (q == 0) attnc[j] = red[0][jj] + red[1][jj] + red[2][jj] + red[3][jj] + bsa[j];
}

// ---------------- weight transpose fp32[K][N] -> fp16[N][K] ----------------
__global__ __launch_bounds__(256) void wtrans(const float* __restrict__ W, u16* __restrict__ WT, int K, int N) {
  __shared__ float tile[64][65];
  const int n0 = blockIdx.x * 64, k0 = blockIdx.y * 64;
  const int t = threadIdx.x;
  #pragma unroll
  for (int i = 0; i < 16; ++i) {
    const int fl = i * 256 + t, r = fl >> 6, c = fl & 63;
    tile[r][c] = W[(size_t)(k0 + r) * N + n0 + c];
  }
  __syncthreads();
  #pragma unroll
  for (int i = 0; i < 16; ++i) {
    const int fl = i * 256 + t, r = fl >> 6, c = fl & 63;
    WT[(size_t)(n0 + r) * K + k0 + c] = f2h(tile[c][r]);
  }
}

// ---------------- fused residual LayerNorm, wave per row ----------------
template <int MODE>
__global__ __launch_bounds__(256) void ln_k(const void* __restrict__ Ap, const void* __restrict__ Bp,
                                            const float* __restrict__ cv, const float* __restrict__ g,
                                            const float* __restrict__ be, void* __restrict__ outp) {
  const int row = blockIdx.x * 4 + (threadIdx.x >> 6);
  const int l = threadIdx.x & 63;
  const size_t base = (size_t)row * DIMn + l * 8;
  float v[8];
  if (MODE == 0 || MODE == 2) {
    const float* a = (const float*)Ap + base;
    float4 x0 = *(const float4*)a;
    float4 x1 = *(const float4*)(a + 4);
    v[0] = x0.x; v[1] = x0.y; v[2] = x0.z; v[3] = x0.w;
    v[4] = x1.x; v[5] = x1.y; v[6] = x1.z; v[7] = x1.w;
  } else {
    short8 s = *(const short8*)((const u16*)Ap + base);
    #pragma unroll
    for (int i = 0; i < 8; ++i) v[i] = h2f((u16)s[i]);
  }
  if (MODE == 0) {
    float4 c0 = *(const float4*)(cv + l * 8);
    float4 c1 = *(const float4*)(cv + l * 8 + 4);
    v[0] += c0.x; v[1] += c0.y; v[2] += c0.z; v[3] += c0.w;
    v[4] += c1.x; v[5] += c1.y; v[6] += c1.z; v[7] += c1.w;
  } else if (MODE == 1) {
    const float* b = (const float*)Bp + base;
    float4 x0 = *(const float4*)b;
    float4 x1 = *(const float4*)(b + 4);
    v[0] += x0.x; v[1] += x0.y; v[2] += x0.z; v[3] += x0.w;
    v[4] += x1.x; v[5] += x1.y; v[6] += x1.z; v[7] += x1.w;
  } else {
    short8 s2 = *(const short8*)((const u16*)Bp + base);
    #pragma unroll
    for (int i = 0; i < 8; ++i) v[i] += h2f((u16)s2[i]);
  }
  float s = 0.f;
  #pragma unroll
  for (int i = 0; i < 8; ++i) s += v[i];
  s = wredsum(s);
  const float mean = s * (1.0f / 512.0f);
  float q = 0.f;
  #pragma unroll
  for (int i = 0; i < 8; ++i) { const float d = v[i] - mean; q += d * d; }
  q = wredsum(q);
  const float rs = rsqrtf(q * (1.0f / 512.0f) + 1e-6f);
  float gg[8], bb[8];
  {
    float4 g0 = *(const float4*)(g + l * 8);
    float4 g1 = *(const float4*)(g + l * 8 + 4);
    float4 b0 = *(const float4*)(be + l * 8);
    float4 b1 = *(const float4*)(be + l * 8 + 4);
    gg[0] = g0.x; gg[1] = g0.y; gg[2] = g0.z; gg[3] = g0.w;
    gg[4] = g1.x; gg[5] = g1.y; gg[6] = g1.z; gg[7] = g1.w;
    bb[0] = b0.x; bb[1] = b0.y; bb[2] = b0.z; bb[3] = b0.w;
    bb[4] = b1.x; bb[5] = b1.y; bb[6] = b1.z; bb[7] = b1.w;
  }
  float y[8];
  #pragma unroll
  for (int i = 0; i < 8; ++i) y[i] = (v[i] - mean) * rs * gg[i] + bb[i];
  if (MODE == 2) {
    float* o = (float*)outp + base;
    *(float4*)o = make_float4(y[0], y[1], y[2], y[3]);
    *(float4*)(o + 4) = make_float4(y[4], y[5], y[6], y[7]);
  } else {
    short8 o;
    #pragma unroll
    for (int i = 0; i < 8; ++i) o[i] = (short)f2h(y[i]);
    *(short8*)((u16*)outp + base) = o;
  }
}

// ---------------- 8-phase GEMM: 256x256 tile, BK=64, 2 dbuf (128KB), swizzled LDS ----------------
// Per K-tile: 4 phases x {ds_read quadrant(+B at q0) | stage next tile (q0,q1) | barrier |
// lgkmcnt(0)+sched_barrier | setprio(1) 16 MFMA setprio(0) | barrier}. vmcnt(0) only at q3.
// Swizzle (T2, both-sides): LDS dest linear; SOURCE chunk = c^(row&7); READ chunk = c^(r16&7).
// Race-free: stages write buf b^1 (reads target b); next tile read only after q3 vmcnt(0)+barrier.
#define CROW 272
template <bool GELU, bool OBF>
__global__ __launch_bounds__(512) void gemm8p(const u16* __restrict__ A, const u16* __restrict__ BT,
                                              const float* __restrict__ bias, u16* __restrict__ OB,
                                              float* __restrict__ OF, int Ni, int Ki, int gridX) {
  __shared__ u16 smem[65536];   // 128KB: 2 bufs x (A[256][64] | B[256][64]) f16
  const int tid = threadIdx.x;
  const int l = tid & 63, wid = tid >> 6, wr = wid >> 2, wc = wid & 3;

  int wg = blockIdx.x;
  const int nwg = gridDim.x;
  if ((nwg & 7) == 0) {
    const int q = nwg >> 3;
    wg = (wg & 7) * q + (wg >> 3);
  }
  const int bx = wg % gridX, by = wg / gridX;
  const int m0 = by * 256, n0 = bx * 256;
  const int r16 = l & 15, g4 = l >> 4;

  // staging source: thread covers LDS row srow, chunk (tid&7); fetch global chunk^(row&7)
  const int srow = tid >> 3;
  const int schunk8 = ((tid & 7) ^ (srow & 7)) * 8;
  const u16* gA = A  + (size_t)(m0 + srow) * (size_t)Ki + schunk8;
  const u16* gB = BT + (size_t)(n0 + srow) * (size_t)Ki + schunk8;
  const size_t r64 = (size_t)64 * Ki, r128 = (size_t)128 * Ki, r192 = (size_t)192 * Ki;
  const int ld = tid * 8;

  // swizzled read chunk offsets (u16 units); row&7 == r16&7 for all frags
  const int c0 = (g4 ^ (r16 & 7)) * 8;
  const int c1 = ((4 + g4) ^ (r16 & 7)) * 8;

  f32x4 acc[8][4] = {};
  const int NT = Ki >> 6;

  // prologue: tile 0 -> buf 0 (8 issues), drain, barrier
  gld16(gA, &smem[ld]);
  gld16(gA + r64, &smem[4096 + ld]);
  gld16(gB, &smem[16384 + ld]);
  gld16(gB + r64, &smem[20480 + ld]);
  gld16(gA + r128, &smem[8192 + ld]);
  gld16(gA + r192, &smem[12288 + ld]);
  gld16(gB + r128, &smem[24576 + ld]);
  gld16(gB + r192, &smem[28672 + ld]);
  asm volatile("s_waitcnt vmcnt(0)" ::: "memory");
  hard_barrier();

  for (int kt = 0; kt < NT; ++kt) {
    const int b = kt & 1;
    const u16* base = smem + b * 32768;
    u16* nb = smem + (b ^ 1) * 32768;
    const int nk = (kt + 1) * 64;
    half8 bf[4][2];
    #pragma unroll
    for (int q = 0; q < 4; ++q) {
      half8 af[2][2];
      #pragma unroll
      for (int m2 = 0; m2 < 2; ++m2) {
        const int ao = (wr * 128 + (q * 2 + m2) * 16 + r16) * 64;
        af[m2][0] = *(const half8*)&base[ao + c0];
        af[m2][1] = *(const half8*)&base[ao + c1];
      }
      if (q == 0) {
        #pragma unroll
        for (int ni = 0; ni < 4; ++ni) {
          const int bo = 16384 + (wc * 64 + ni * 16 + r16) * 64;
          bf[ni][0] = *(const half8*)&base[bo + c0];
          bf[ni][1] = *(const half8*)&base[bo + c1];
        }
      }
      if (kt + 1 < NT) {
        if (q == 0) {
          gld16(gA + nk, &nb[ld]);
          gld16(gA + nk + r64, &nb[4096 + ld]);
          gld16(gB + nk, &nb[16384 + ld]);
          gld16(gB + nk + r64, &nb[20480 + ld]);
        } else if (q == 1) {
          gld16(gA + nk + r128, &nb[8192 + ld]);
          gld16(gA + nk + r192, &nb[12288 + ld]);
          gld16(gB + nk + r128, &nb[24576 + ld]);
          gld16(gB + nk + r192, &nb[28672 + ld]);
        }
      }
      if (q == 3) asm volatile("s_waitcnt vmcnt(0)" ::: "memory");
      hard_barrier();
      asm volatile("s_waitcnt lgkmcnt(0)" ::: "memory");
      __builtin_amdgcn_sched_barrier(0);
      __builtin_amdgcn_s_setprio(1);
      #pragma unroll
      for (int s = 0; s < 2; ++s)
        #pragma unroll
        for (int m2 = 0; m2 < 2; ++m2)
          #pragma unroll
          for (int ni = 0; ni < 4; ++ni)
            acc[q * 2 + m2][ni] = __builtin_amdgcn_mfma_f32_16x16x32_f16(af[m2][s], bf[ni][s], acc[q * 2 + m2][ni], 0, 0, 0);
      __builtin_amdgcn_s_setprio(0);
      hard_barrier();
    }
  }

  if (OBF) {
    // r14-proven 2-pass all-wave epilogue
    u16* Cs = smem;
    float bv[4];
    #pragma unroll
    for (int ni = 0; ni < 4; ++ni) bv[ni] = bias[n0 + wc * 64 + ni * 16 + r16];
    #pragma unroll
    for (int p = 0; p < 2; ++p) {
      #pragma unroll
      for (int mi4 = 0; mi4 < 4; ++mi4) {
        const int mi = p * 4 + mi4;
        #pragma unroll
        for (int ni = 0; ni < 4; ++ni) {
          const int colL = wc * 64 + ni * 16 + r16;
          #pragma unroll
          for (int r = 0; r < 4; ++r) {
            float v = acc[mi][ni][r] + bv[ni];
            if (GELU) v = fast_gelu(v);
            Cs[wr * (64 * CROW) + (mi4 * 16 + g4 * 4 + r) * CROW + colL] = f2h(v);
          }
        }
      }
      hard_barrier();
      #pragma unroll
      for (int j = 0; j < 8; ++j) {
        const int s = tid + j * 512;
        const int wrS = s >> 11;
        const int rowL = (s & 2047) >> 5;
        const int c8 = s & 31;
        *(short8*)(OB + (size_t)(m0 + wrS * 128 + p * 64 + rowL) * Ni + n0 + c8 * 8) =
            *(const short8*)&Cs[wrS * (64 * CROW) + rowL * CROW + c8 * 8];
      }
      if (p == 0) hard_barrier();
    }
  } else {
    #pragma unroll
    for (int ni = 0; ni < 4; ++ni) {
      const int col = n0 + wc * 64 + ni * 16 + r16;
      const float bvv = bias[col];
      #pragma unroll
      for (int mi = 0; mi < 8; ++mi) {
        const int rowb = m0 + wr * 128 + mi * 16 + g4 * 4;
        #pragma unroll
        for (int r = 0; r < 4; ++r) {
          float v = acc[mi][ni][r] + bvv;
          if (GELU) v = fast_gelu(v);
          OF[(size_t)(rowb + r) * Ni + col] = v;
        }
      }
    }
  }
}

// ---------------- enc-dec attention: per (t,h) a 32x32 batch-attention ----------------
__global__ __launch_bounds__(64) void attn_k(const u16* __restrict__ qe, const float* __restrict__ kin,
                                             const float* __restrict__ vin, u16* __restrict__ wa2) {
  const int t = blockIdx.x >> 3;
  const int h = blockIdx.x & 7;
  const int l = threadIdx.x;
  __shared__ u16 Kq[32 * 80];
  __shared__ u16 Qq[32 * 80];
  __shared__ u16 VT[64 * 48];
  __shared__ u16 Ps[32 * 48];

  const float* kp = kin + (size_t)blockIdx.x * 2048;
  const float* vp = vin + (size_t)blockIdx.x * 2048;
  #pragma unroll
  for (int i = 0; i < 8; ++i) {
    const int fl = i * 256 + l * 4;
    const int r = fl >> 6, c = fl & 63;
    float4 kv = *(const float4*)(kp + fl);
    float4 vv = *(const float4*)(vp + fl);
    *(u32*)&Kq[r * 80 + c]     = pack2h(kv.x, kv.y);
    *(u32*)&Kq[r * 80 + c + 2] = pack2h(kv.z, kv.w);
    VT[(c + 0) * 48 + r] = f2h(vv.x);
    VT[(c + 1) * 48 + r] = f2h(vv.y);
    VT[(c + 2) * 48 + r] = f2h(vv.z);
    VT[(c + 3) * 48 + r] = f2h(vv.w);
  }
  {
    const int qb = l >> 1, hf = l & 1;
    const u16* qp = qe + (size_t)(qb * Tn + t) * DIMn + h * HDn + hf * 32;
    #pragma unroll
    for (int j = 0; j < 4; ++j) {
      short8 d = *(const short8*)(qp + j * 8);
      *(short8*)&Qq[qb * 80 + hf * 32 + j * 8] = d;
    }
  }
  __syncthreads();

  const int r16 = l & 15, g4 = l >> 4;
  f32x4 sacc[2][2] = {};
  #pragma unroll
  for (int kk = 0; kk < 2; ++kk) {
    half8 aQ0 = *(const half8*)&Qq[r16 * 80 + kk * 32 + g4 * 8];
    half8 aQ1 = *(const half8*)&Qq[(16 + r16) * 80 + kk * 32 + g4 * 8];
    half8 bK0 = *(const half8*)&Kq[r16 * 80 + kk * 32 + g4 * 8];
    half8 bK1 = *(const half8*)&Kq[(16 + r16) * 80 + kk * 32 + g4 * 8];
    sacc[0][0] = __builtin_amdgcn_mfma_f32_16x16x32_f16(aQ0, bK0, sacc[0][0], 0, 0, 0);
    sacc[0][1] = __builtin_amdgcn_mfma_f32_16x16x32_f16(aQ0, bK1, sacc[0][1], 0, 0, 0);
    sacc[1][0] = __builtin_amdgcn_mfma_f32_16x16x32_f16(aQ1, bK0, sacc[1][0], 0, 0, 0);
    sacc[1][1] = __builtin_amdgcn_mfma_f32_16x16x32_f16(aQ1, bK1, sacc[1][1], 0, 0, 0);
  }
  #pragma unroll
  for (int m = 0; m < 2; ++m) {
    #pragma unroll
    for (int r = 0; r < 4; ++r) {
      const float a0 = sacc[m][0][r] * 0.125f;
      const float a1 = sacc[m][1][r] * 0.125f;
      float mx = fmaxf(a0, a1);
      #pragma unroll
      for (int d = 1; d < 16; d <<= 1) mx = fmaxf(mx, __shfl_xor(mx, d, 64));
      const float e0 = __expf(a0 - mx), e1 = __expf(a1 - mx);
      float sm = e0 + e1;
      #pragma unroll
      for (int d = 1; d < 16; d <<= 1) sm += __shfl_xor(sm, d, 64);
      const float inv = 1.0f / sm;
      const int rr = m * 16 + g4 * 4 + r;
      Ps[rr * 48 + r16]      = f2h(e0 * inv);
      Ps[rr * 48 + 16 + r16] = f2h(e1 * inv);
    }
  }
  __syncthreads();

  half8 aP0 = *(const half8*)&Ps[r16 * 48 + g4 * 8];
  half8 aP1 = *(const half8*)&Ps[(16 + r16) * 48 + g4 * 8];
  f32x4 oacc[2][4] = {};
  #pragma unroll
  for (int nn = 0; nn < 4; ++nn) {
    half8 bV = *(const half8*)&VT[(nn * 16 + r16) * 48 + g4 * 8];
    oacc[0][nn] = __builtin_amdgcn_mfma_f32_16x16x32_f16(aP0, bV, oacc[0][nn], 0, 0, 0);
    oacc[1][nn] = __builtin_amdgcn_mfma_f32_16x16x32_f16(aP1, bV, oacc[1][nn], 0, 0, 0);
  }
  #pragma unroll
  for (int m = 0; m < 2; ++m) {
    #pragma unroll
    for (int r = 0; r < 4; ++r) {
      const int qb = m * 16 + g4 * 4 + r;
      u16* op = wa2 + (size_t)(qb * Tn + t) * DIMn + h * HDn;
      #pragma unroll
      for (int nn = 0; nn < 4; ++nn)
        op[nn * 16 + r16] = f2h(oacc[m][nn][r]);
    }
  }
}

extern "C" void kernel_launch(void* const* d_in, const int* in_sizes, int n_in,
                              void* d_out, int out_size, void* d_ws, size_t ws_size,
                              hipStream_t stream) {
  (void)in_sizes; (void)n_in; (void)out_size;
  const float* x    = (const float*)d_in[0];
  const float* kin  = (const float*)d_in[1];
  const float* vin  = (const float*)d_in[2];
  const float* Wqkv = (const float*)d_in[3];
  const float* bqkv = (const float*)d_in[4];
  const float* Wsa  = (const float*)d_in[5];
  const float* bsa  = (const float*)d_in[6];
  const float* Wq   = (const float*)d_in[7];
  const float* bq   = (const float*)d_in[8];
  const float* Wed  = (const float*)d_in[9];
  const float* bed  = (const float*)d_in[10];
  const float* g1   = (const float*)d_in[11];
  const float* be1  = (const float*)d_in[12];
  const float* g2   = (const float*)d_in[13];
  const float* be2  = (const float*)d_in[14];
  const float* g3   = (const float*)d_in[15];
  const float* be3  = (const float*)d_in[16];
  const float* W1   = (const float*)d_in[17];
  const float* b1   = (const float*)d_in[18];
  const float* W2   = (const float*)d_in[19];
  const float* b2   = (const float*)d_in[20];

  // ---- workspace layout ----
  char* ws = (char*)d_ws;
  float* xs    = (float*)(ws);
  float* SVp   = (float*)(ws + (2 << 10));
  float* attnc = (float*)(ws + (4 << 10));
  float* part  = (float*)(ws + (6 << 10));
  u16* wqT  = (u16*)(ws + (1 << 20));
  u16* wedT = (u16*)(ws + (1 << 20) + (512 << 10));
  u16* w1T  = (u16*)(ws + (2 << 20));
  u16* w2T  = (u16*)(ws + (4 << 20));
  u16* Abuf = (u16*)(ws + (6 << 20));
  const size_t HOFF = 38ull << 20;
  u16* hmid = (u16*)(ws + HOFF);

  u16* an1  = Abuf;
  u16* wa2  = Abuf;
  u16* an2b = Abuf;
  u16*   qe   = (u16*)d_out;
  u16*   a2bf = (u16*)d_out;
  float* zf   = (float*)d_out;

  long long avail = (long long)ws_size - (long long)HOFF;
  int crows = (avail > 0) ? (int)(avail / (HIDn * 2)) : 256;
  crows = (crows / 256) * 256;
  if (crows < 256) crows = 256;
  if (crows > Mn) crows = Mn;

  colsum1<<<256, 256, 0, stream>>>(x, part);
  colsum2<<<2, 256, 0, stream>>>(part, xs);
  sv_k<<<8, 256, 0, stream>>>(xs, Wqkv, bqkv, SVp);
  attnc2_k<<<8, 256, 0, stream>>>(SVp, Wsa, bsa, attnc);

  wtrans<<<dim3(8, 8),  256, 0, stream>>>(Wq,  wqT,  512, 512);
  wtrans<<<dim3(8, 8),  256, 0, stream>>>(Wed, wedT, 512, 512);
  wtrans<<<dim3(32, 8), 256, 0, stream>>>(W1,  w1T,  512, 2048);
  wtrans<<<dim3(8, 32), 256, 0, stream>>>(W2,  w2T,  2048, 512);

  // an1 = LN(x + attn_c)  (f16, Abuf)
  ln_k<0><<<Mn / 4, 256, 0, stream>>>(x, nullptr, attnc, g1, be1, an1);
  // qe = an1 @ Wq + bq  (f16, d_out lower)
  gemm8p<false, true><<<256, 512, 0, stream>>>(an1, wqT, bq, qe, nullptr, 512, 512, 2);
  // wa2 (f16, Abuf; an1 dead)
  attn_k<<<Tn * Hn, 64, 0, stream>>>(qe, kin, vin, wa2);
  // attn2 = wa2 @ Wed + bed (f16, d_out lower; qe dead)
  gemm8p<false, true><<<256, 512, 0, stream>>>(wa2, wedT, bed, a2bf, nullptr, 512, 512, 2);
  // an2 = LN(attn2 + x)  (f16, Abuf; wa2 dead)
  ln_k<1><<<Mn / 4, 256, 0, stream>>>(a2bf, x, nullptr, g2, be2, an2b);
  // MLP chunked: hmid = gelu(an2 @ W1 + b1) [ws]; z = hmid @ W2 + b2 (f32, d_out; attn2 dead)
  for (int r0 = 0; r0 < Mn; r0 += crows) {
    int rc = Mn - r0; if (rc > crows) rc = crows;
    gemm8p<true, true><<<8 * (rc / 256), 512, 0, stream>>>(an2b + (size_t)r0 * DIMn, w1T, b1, hmid, nullptr, HIDn, DIMn, 8);
    gemm8p<false, false><<<2 * (rc / 256), 512, 0, stream>>>(hmid, w2T, b2, nullptr, zf + (size_t)r0 * DIMn, DIMn, HIDn, 2);
  }
  // out = LN(z + an2): fp32 in-place on d_out, f16 an2 from ws
  ln_k<2><<<Mn / 4, 256, 0, stream>>>(zf, an2b, nullptr, g3, be3, d_out);
}

// Round 17
// 399.489 us; speedup vs baseline: 1.0619x; 1.0619x over previous
//
#include <hip/hip_runtime.h>
#include <hip/hip_bf16.h>
#include <math.h>

#define Bn 32
#define Tn 1024
#define DIMn 512
#define Hn 8
#define HDn 64
#define HIDn 2048
#define Mn 32768

using short8 = __attribute__((ext_vector_type(8))) short;
using half8  = __attribute__((ext_vector_type(8))) _Float16;
using f32x4  = __attribute__((ext_vector_type(4))) float;
typedef unsigned short u16;
typedef unsigned int   u32;

__device__ __forceinline__ u16 f2h(float x) {
  _Float16 h = (_Float16)x;
  return __builtin_bit_cast(u16, h);
}
__device__ __forceinline__ float h2f(u16 u) {
  return (float)__builtin_bit_cast(_Float16, u);
}
__device__ __forceinline__ u32 pack2h(float a, float b) {
  return (u32)f2h(a) | ((u32)f2h(b) << 16);
}
__device__ __forceinline__ void gld16(const void* g, void* l) {
  __builtin_amdgcn_global_load_lds((const __attribute__((address_space(1))) u32*)g,
                                   (__attribute__((address_space(3))) u32*)l, 16, 0, 0);
}
__device__ __forceinline__ float wredsum(float v) {
  #pragma unroll
  for (int d = 1; d < 64; d <<= 1) v += __shfl_xor(v, d, 64);
  return v;
}
__device__ __forceinline__ void hard_barrier() {
  asm volatile("" ::: "memory");
  __builtin_amdgcn_s_barrier();
  asm volatile("" ::: "memory");
}
// Abramowitz-Stegun 7.1.26 erf (|err|<1.5e-7) -> exact GELU at f16 resolution
__device__ __forceinline__ float fast_gelu(float v) {
  const float ax = fabsf(v) * 0.70710678118654752f;
  const float t = 1.0f / (1.0f + 0.3275911f * ax);
  const float p = ((((1.061405429f * t - 1.453152027f) * t) + 1.421413741f) * t - 0.284496736f) * t + 0.254829592f;
  const float y = 1.0f - p * t * __expf(-ax * ax);
  const float erfv = (v >= 0.f) ? y : -y;
  return 0.5f * v * (1.0f + erfv);
}

// ---------------- column sums of x ----------------
__global__ __launch_bounds__(256) void colsum1(const float* __restrict__ x, float* __restrict__ part) {
  const int b = blockIdx.x, t = threadIdx.x;
  const float* p = x + (size_t)b * 128 * DIMn;
  float a0 = 0.f, a1 = 0.f;
  for (int r = 0; r < 128; ++r) {
    a0 += p[r * DIMn + t];
    a1 += p[r * DIMn + t + 256];
  }
  part[b * DIMn + t] = a0;
  part[b * DIMn + t + 256] = a1;
}

__global__ __launch_bounds__(256) void colsum2(const float* __restrict__ part, float* __restrict__ xs) {
  const int c = blockIdx.x * 256 + threadIdx.x;
  float a = 0.f;
  for (int b = 0; b < 256; ++b) a += part[b * DIMn + c];
  xs[c] = a;
}

// SVp[h][f] = XS . Wqkv[:,1024+h*64+f] + 32768*bqkv[...]   (grid 8, 256 thr)
__global__ __launch_bounds__(256) void sv_k(const float* __restrict__ xs, const float* __restrict__ Wqkv,
                                            const float* __restrict__ bqkv, float* __restrict__ SVp) {
  __shared__ float xsh[512];
  __shared__ float red[4][64];
  const int h = blockIdx.x, q = threadIdx.x >> 6, f = threadIdx.x & 63;
  xsh[threadIdx.x] = xs[threadIdx.x];
  xsh[threadIdx.x + 256] = xs[threadIdx.x + 256];
  __syncthreads();
  const int colb = 2 * DIMn + h * HDn + f;
  float acc = 0.f;
  for (int i = q * 128; i < q * 128 + 128; ++i) acc += xsh[i] * Wqkv[(size_t)i * 1536 + colb];
  red[q][f] = acc;
  __syncthreads();
  if (q == 0)
    SVp[h * 64 + f] = red[0][f] + red[1][f] + red[2][f] + red[3][f] + 32768.0f * bqkv[colb];
}

// attnc[j] = bsa[j] + sum_i SV[i&63]*Wsa[i][j]   (grid 8, 256 thr)
__global__ __launch_bounds__(256) void attnc2_k(const float* __restrict__ SVp, const float* __restrict__ Wsa,
                                                const float* __restrict__ bsa, float* __restrict__ attnc) {
  __shared__ float SVs[64];
  __shared__ float red[4][64];
  const int q = threadIdx.x >> 6, jj = threadIdx.x & 63;
  if (threadIdx.x < 64) {
    float s = 0.f;
    #pragma unroll
    for (int h = 0; h < 8; ++h) s += SVp[h * 64 + threadIdx.x];
    SVs[threadIdx.x] = s;
  }
  __syncthreads();
  const int j = blockIdx.x * 64 + jj;
  float acc = 0.f;
  for (int i = q * 128; i < q * 128 + 128; ++i) acc += SVs[i & 63] * Wsa[(size_t)i * DIMn + j];
  red[q][jj] = acc;
  __syncthreads();
  if (q == 0) attnc[j] = red[0][jj] + red[1][jj] + red[2][jj] + red[3][jj] + bsa[j];
}

// ---------------- weight transpose fp32[K][N] -> fp16[N][K] ----------------
__global__ __launch_bounds__(256) void wtrans(const float* __restrict__ W, u16* __restrict__ WT, int K, int N) {
  __shared__ float tile[64][65];
  const int n0 = blockIdx.x * 64, k0 = blockIdx.y * 64;
  const int t = threadIdx.x;
  #pragma unroll
  for (int i = 0; i < 16; ++i) {
    const int fl = i * 256 + t, r = fl >> 6, c = fl & 63;
    tile[r][c] = W[(size_t)(k0 + r) * N + n0 + c];
  }
  __syncthreads();
  #pragma unroll
  for (int i = 0; i < 16; ++i) {
    const int fl = i * 256 + t, r = fl >> 6, c = fl & 63;
    WT[(size_t)(n0 + r) * K + k0 + c] = f2h(tile[c][r]);
  }
}

// ---------------- fused residual LayerNorm, wave per row ----------------
template <int MODE>
__global__ __launch_bounds__(256) void ln_k(const void* __restrict__ Ap, const void* __restrict__ Bp,
                                            const float* __restrict__ cv, const float* __restrict__ g,
                                            const float* __restrict__ be, void* __restrict__ outp) {
  const int row = blockIdx.x * 4 + (threadIdx.x >> 6);
  const int l = threadIdx.x & 63;
  const size_t base = (size_t)row * DIMn + l * 8;
  float v[8];
  if (MODE == 0 || MODE == 2) {
    const float* a = (const float*)Ap + base;
    float4 x0 = *(const float4*)a;
    float4 x1 = *(const float4*)(a + 4);
    v[0] = x0.x; v[1] = x0.y; v[2] = x0.z; v[3] = x0.w;
    v[4] = x1.x; v[5] = x1.y; v[6] = x1.z; v[7] = x1.w;
  } else {
    short8 s = *(const short8*)((const u16*)Ap + base);
    #pragma unroll
    for (int i = 0; i < 8; ++i) v[i] = h2f((u16)s[i]);
  }
  if (MODE == 0) {
    float4 c0 = *(const float4*)(cv + l * 8);
    float4 c1 = *(const float4*)(cv + l * 8 + 4);
    v[0] += c0.x; v[1] += c0.y; v[2] += c0.z; v[3] += c0.w;
    v[4] += c1.x; v[5] += c1.y; v[6] += c1.z; v[7] += c1.w;
  } else if (MODE == 1) {
    const float* b = (const float*)Bp + base;
    float4 x0 = *(const float4*)b;
    float4 x1 = *(const float4*)(b + 4);
    v[0] += x0.x; v[1] += x0.y; v[2] += x0.z; v[3] += x0.w;
    v[4] += x1.x; v[5] += x1.y; v[6] += x1.z; v[7] += x1.w;
  } else {
    short8 s2 = *(const short8*)((const u16*)Bp + base);
    #pragma unroll
    for (int i = 0; i < 8; ++i) v[i] += h2f((u16)s2[i]);
  }
  float s = 0.f;
  #pragma unroll
  for (int i = 0; i < 8; ++i) s += v[i];
  s = wredsum(s);
  const float mean = s * (1.0f / 512.0f);
  float q = 0.f;
  #pragma unroll
  for (int i = 0; i < 8; ++i) { const float d = v[i] - mean; q += d * d; }
  q = wredsum(q);
  const float rs = rsqrtf(q * (1.0f / 512.0f) + 1e-6f);
  float gg[8], bb[8];
  {
    float4 g0 = *(const float4*)(g + l * 8);
    float4 g1 = *(const float4*)(g + l * 8 + 4);
    float4 b0 = *(const float4*)(be + l * 8);
    float4 b1 = *(const float4*)(be + l * 8 + 4);
    gg[0] = g0.x; gg[1] = g0.y; gg[2] = g0.z; gg[3] = g0.w;
    gg[4] = g1.x; gg[5] = g1.y; gg[6] = g1.z; gg[7] = g1.w;
    bb[0] = b0.x; bb[1] = b0.y; bb[2] = b0.z; bb[3] = b0.w;
    bb[4] = b1.x; bb[5] = b1.y; bb[6] = b1.z; bb[7] = b1.w;
  }
  float y[8];
  #pragma unroll
  for (int i = 0; i < 8; ++i) y[i] = (v[i] - mean) * rs * gg[i] + bb[i];
  if (MODE == 2) {
    float* o = (float*)outp + base;
    *(float4*)o = make_float4(y[0], y[1], y[2], y[3]);
    *(float4*)(o + 4) = make_float4(y[4], y[5], y[6], y[7]);
  } else {
    short8 o;
    #pragma unroll
    for (int i = 0; i < 8; ++i) o[i] = (short)f2h(y[i]);
    *(short8*)((u16*)outp + base) = o;
  }
}

// ---------------- GEMM kernel A: 128x128 tile (r13/r15-proven: 155us on MLP1) ----------------
#define CPAD 132
template <bool GELU, bool OBF>
__global__ __launch_bounds__(256) void gemm128(const u16* __restrict__ A, const u16* __restrict__ BT,
                                               const float* __restrict__ bias, u16* __restrict__ OB,
                                               float* __restrict__ OF, int Ni, int Ki, int gridX) {
  __shared__ u16 smem[3 * 8192];
  const int tid = threadIdx.x;
  const int l = tid & 63, w = tid >> 6, wr = w >> 1, wc = w & 1;

  int wg = blockIdx.x;
  const int nwg = gridDim.x;
  if ((nwg & 7) == 0) {
    const int q = nwg >> 3;
    wg = (wg & 7) * q + (wg >> 3);
  }
  const int bx = wg % gridX, by = wg / gridX;
  const int m0 = by * 128, n0 = bx * 128;
  const int r16 = l & 15, g4 = l >> 4;

  const int schunk = (tid & 3) ^ ((tid >> 2) & 3);
  const u16* ga = A + (size_t)(m0 + (tid >> 2)) * (size_t)Ki + schunk * 8;
  const u16* gb = BT + (size_t)(n0 + (tid >> 2)) * (size_t)Ki + schunk * 8;
  const int ldst = tid * 8;

  const int g4s = g4 ^ (r16 & 3);
  int aoff[4], boff[4];
  #pragma unroll
  for (int i = 0; i < 4; ++i) {
    aoff[i] = (wr * 64 + i * 16 + r16) * 32 + g4s * 8;
    boff[i] = 4096 + (wc * 64 + i * 16 + r16) * 32 + g4s * 8;
  }
  f32x4 acc[4][4] = {};

  const int nt = Ki >> 5;
  auto STAGE = [&](int t, int b) {
    u16* base = smem + b * 8192;
    const int kk = t * 32;
    gld16(ga + kk, &base[ldst]);
    gld16(ga + kk + (size_t)64 * Ki, &base[ldst + 2048]);
    gld16(gb + kk, &base[4096 + ldst]);
    gld16(gb + kk + (size_t)64 * Ki, &base[4096 + ldst + 2048]);
  };

  STAGE(0, 0);
  STAGE(1, 1);
  int b0 = 0, b1 = 1, b2 = 2;
  for (int t = 0; t < nt; ++t) {
    if (t < nt - 1) asm volatile("s_waitcnt vmcnt(4)" ::: "memory");
    else            asm volatile("s_waitcnt vmcnt(0)" ::: "memory");
    hard_barrier();
    if (t + 2 < nt) STAGE(t + 2, b2);
    const u16* base = smem + b0 * 8192;
    half8 af[4], bf[4];
    #pragma unroll
    for (int i = 0; i < 4; ++i) af[i] = *(const half8*)&base[aoff[i]];
    #pragma unroll
    for (int i = 0; i < 4; ++i) bf[i] = *(const half8*)&base[boff[i]];
    #pragma unroll
    for (int mi = 0; mi < 4; ++mi)
      #pragma unroll
      for (int ni = 0; ni < 4; ++ni)
        acc[mi][ni] = __builtin_amdgcn_mfma_f32_16x16x32_f16(af[mi], bf[ni], acc[mi][ni], 0, 0, 0);
    hard_barrier();
    const int tb = b0; b0 = b1; b1 = b2; b2 = tb;
  }

  if (OBF) {
    u16* Cs = smem;
    #pragma unroll
    for (int ni = 0; ni < 4; ++ni) {
      const int col = wc * 64 + ni * 16 + r16;
      const float bv = bias[n0 + col];
      #pragma unroll
      for (int mi = 0; mi < 4; ++mi) {
        const int rowb = wr * 64 + mi * 16 + g4 * 4;
        #pragma unroll
        for (int r = 0; r < 4; ++r) {
          float v = acc[mi][ni][r] + bv;
          if (GELU) v = fast_gelu(v);
          Cs[(rowb + r) * CPAD + col] = f2h(v);
        }
      }
    }
    hard_barrier();
    const int rr = tid >> 4;
    const int c0 = (tid & 15) * 8;
    #pragma unroll
    for (int j = 0; j < 8; ++j) {
      const int row = rr + j * 16;
      *(short8*)(OB + (size_t)(m0 + row) * Ni + n0 + c0) = *(const short8*)&Cs[row * CPAD + c0];
    }
  } else {
    #pragma unroll
    for (int ni = 0; ni < 4; ++ni) {
      const int col = n0 + wc * 64 + ni * 16 + r16;
      const float bv = bias[col];
      #pragma unroll
      for (int mi = 0; mi < 4; ++mi) {
        const int rowb = m0 + wr * 64 + mi * 16 + g4 * 4;
        #pragma unroll
        for (int r = 0; r < 4; ++r) {
          float v = acc[mi][ni][r] + bv;
          if (GELU) v = fast_gelu(v);
          OF[(size_t)(rowb + r) * Ni + col] = v;
        }
      }
    }
  }
}

// ---------------- GEMM kernel B: 256x256 tile (r14/r15-proven for N=512 shapes) ----------------
#define CROW 272
template <bool GELU, bool OBF>
__global__ __launch_bounds__(512) void gemm256(const u16* __restrict__ A, const u16* __restrict__ BT,
                                               const float* __restrict__ bias, u16* __restrict__ OB,
                                               float* __restrict__ OF, int Ni, int Ki, int gridX) {
  __shared__ u16 smem[49152];
  const int tid = threadIdx.x;
  const int l = tid & 63, wid = tid >> 6, wr = wid >> 2, wc = wid & 3;

  int wg = blockIdx.x;
  const int nwg = gridDim.x;
  if ((nwg & 7) == 0) {
    const int q = nwg >> 3;
    wg = (wg & 7) * q + (wg >> 3);
  }
  const int bx = wg % gridX, by = wg / gridX;
  const int m0 = by * 256, n0 = bx * 256;
  const int r16 = l & 15, g4 = l >> 4;

  const int srow = tid >> 2, schunk = (tid & 3) * 8;
  const u16* gaA = A  + (size_t)(m0 + srow) * (size_t)Ki + schunk;
  const u16* gaB = BT + (size_t)(n0 + srow) * (size_t)Ki + schunk;
  const size_t rowskip = (size_t)128 * (size_t)Ki;
  const int ldst = tid * 8;

  int aoff[8], boff[4];
  #pragma unroll
  for (int mi = 0; mi < 8; ++mi) aoff[mi] = (wr * 128 + mi * 16 + r16) * 32 + g4 * 8;
  #pragma unroll
  for (int ni = 0; ni < 4; ++ni) boff[ni] = 8192 + (wc * 64 + ni * 16 + r16) * 32 + g4 * 8;

  f32x4 acc[8][4] = {};
  const int nt = Ki >> 5;

  auto STAGE = [&](int t, int b) {
    u16* base = smem + b * 16384;
    const int kk = t * 32;
    gld16(gaA + kk, &base[ldst]);
    gld16(gaA + kk + rowskip, &base[ldst + 4096]);
    gld16(gaB + kk, &base[8192 + ldst]);
    gld16(gaB + kk + rowskip, &base[8192 + ldst + 4096]);
  };

  STAGE(0, 0);
  STAGE(1, 1);
  int b0 = 0, b1 = 1, b2 = 2;
  for (int t = 0; t < nt; ++t) {
    if (t < nt - 1) asm volatile("s_waitcnt vmcnt(4)" ::: "memory");
    else            asm volatile("s_waitcnt vmcnt(0)" ::: "memory");
    hard_barrier();
    if (t + 2 < nt) STAGE(t + 2, b2);
    const u16* base = smem + b0 * 16384;
    half8 bf[4];
    #pragma unroll
    for (int ni = 0; ni < 4; ++ni) bf[ni] = *(const half8*)&base[boff[ni]];
    #pragma unroll
    for (int mi = 0; mi < 8; ++mi) {
      half8 af = *(const half8*)&base[aoff[mi]];
      #pragma unroll
      for (int ni = 0; ni < 4; ++ni)
        acc[mi][ni] = __builtin_amdgcn_mfma_f32_16x16x32_f16(af, bf[ni], acc[mi][ni], 0, 0, 0);
    }
    hard_barrier();
    const int tb = b0; b0 = b1; b1 = b2; b2 = tb;
  }

  if (OBF) {
    u16* Cs = smem;
    float bv[4];
    #pragma unroll
    for (int ni = 0; ni < 4; ++ni) bv[ni] = bias[n0 + wc * 64 + ni * 16 + r16];
    #pragma unroll
    for (int p = 0; p < 2; ++p) {
      #pragma unroll
      for (int mi4 = 0; mi4 < 4; ++mi4) {
        const int mi = p * 4 + mi4;
        #pragma unroll
        for (int ni = 0; ni < 4; ++ni) {
          const int colL = wc * 64 + ni * 16 + r16;
          #pragma unroll
          for (int r = 0; r < 4; ++r) {
            float v = acc[mi][ni][r] + bv[ni];
            if (GELU) v = fast_gelu(v);
            Cs[wr * (64 * CROW) + (mi4 * 16 + g4 * 4 + r) * CROW + colL] = f2h(v);
          }
        }
      }
      hard_barrier();
      #pragma unroll
      for (int j = 0; j < 8; ++j) {
        const int s = tid + j * 512;
        const int wrS = s >> 11;
        const int rowL = (s & 2047) >> 5;
        const int c8 = s & 31;
        *(short8*)(OB + (size_t)(m0 + wrS * 128 + p * 64 + rowL) * Ni + n0 + c8 * 8) =
            *(const short8*)&Cs[wrS * (64 * CROW) + rowL * CROW + c8 * 8];
      }
      if (p == 0) hard_barrier();
    }
  } else {
    #pragma unroll
    for (int ni = 0; ni < 4; ++ni) {
      const int col = n0 + wc * 64 + ni * 16 + r16;
      const float bvv = bias[col];
      #pragma unroll
      for (int mi = 0; mi < 8; ++mi) {
        const int rowb = m0 + wr * 128 + mi * 16 + g4 * 4;
        #pragma unroll
        for (int r = 0; r < 4; ++r) {
          float v = acc[mi][ni][r] + bvv;
          if (GELU) v = fast_gelu(v);
          OF[(size_t)(rowb + r) * Ni + col] = v;
        }
      }
    }
  }
}

// ---------------- fused MLP2 + final LN: 128 rows x FULL 512 cols per block ----------------
// z = hmid @ w2T + b2 never touches HBM: computed in acc, residual an2 added, LN'd in
// epilogue, f32 written straight to out. r13-proven 3-buf lead-2 skeleton, BK=32, 8 waves
// (2M x 4N), 32 MFMA/wave/K-step. LDS 3 x 40KB = 120KB; epilogue reuses as f32[32][516].
__global__ __launch_bounds__(512) void gemm_mlp2_ln(const u16* __restrict__ A, const u16* __restrict__ BT,
                                                    const float* __restrict__ bias, const u16* __restrict__ an2,
                                                    const float* __restrict__ g, const float* __restrict__ be,
                                                    float* __restrict__ out, int Ki) {
  __shared__ u16 smem[61440];   // 120KB: 3 bufs x (A[128][32]=4096 | B[512][32]=16384) u16
  const int tid = threadIdx.x;
  const int l = tid & 63, wid = tid >> 6, wr = wid >> 2, wc = wid & 3;
  const int m0 = blockIdx.x * 128;
  const int r16 = l & 15, g4 = l >> 4;

  const u16* gA = A  + (size_t)(m0 + (tid >> 2)) * (size_t)Ki + (tid & 3) * 8;
  const u16* gB = BT + (size_t)(tid >> 2) * (size_t)Ki + (tid & 3) * 8;
  const size_t r128 = (size_t)128 * Ki;

  int aoff[4], boff[8];
  #pragma unroll
  for (int mi = 0; mi < 4; ++mi) aoff[mi] = (wr * 64 + mi * 16 + r16) * 32 + g4 * 8;
  #pragma unroll
  for (int ni = 0; ni < 8; ++ni) boff[ni] = 4096 + (wc * 128 + ni * 16 + r16) * 32 + g4 * 8;

  f32x4 acc[4][8] = {};
  const int nt = Ki >> 5;

  auto STAGE = [&](int t, int b) {
    u16* base = smem + b * 20480;
    const int kk = t * 32;
    gld16(gA + kk, &base[tid * 8]);
    #pragma unroll
    for (int j = 0; j < 4; ++j)
      gld16(gB + kk + (size_t)j * r128, &base[4096 + tid * 8 + j * 4096]);
  };

  STAGE(0, 0);
  STAGE(1, 1);
  int b0 = 0, b1 = 1, b2 = 2;
  for (int t = 0; t < nt; ++t) {
    if (t < nt - 1) asm volatile("s_waitcnt vmcnt(5)" ::: "memory");  // tile t's 5 loads done
    else            asm volatile("s_waitcnt vmcnt(0)" ::: "memory");
    hard_barrier();
    if (t + 2 < nt) STAGE(t + 2, b2);
    const u16* base = smem + b0 * 20480;
    half8 af[4];
    #pragma unroll
    for (int mi = 0; mi < 4; ++mi) af[mi] = *(const half8*)&base[aoff[mi]];
    #pragma unroll
    for (int ni = 0; ni < 8; ++ni) {
      half8 bf = *(const half8*)&base[boff[ni]];
      #pragma unroll
      for (int mi = 0; mi < 4; ++mi)
        acc[mi][ni] = __builtin_amdgcn_mfma_f32_16x16x32_f16(af[mi], bf, acc[mi][ni], 0, 0, 0);
    }
    hard_barrier();
    const int tb = b0; b0 = b1; b1 = b2; b2 = tb;
  }

  // epilogue: 4 groups of 32 rows; stage z=acc+bias as f32 in LDS, then wave-per-row LN
  float* Ls = (float*)smem;   // [32][516] f32 = 66KB (<=120KB)
  float bv[8];
  #pragma unroll
  for (int ni = 0; ni < 8; ++ni) bv[ni] = bias[wc * 128 + ni * 16 + r16];
  #pragma unroll
  for (int rg = 0; rg < 4; ++rg) {
    if (wr == (rg >> 1)) {
      #pragma unroll
      for (int mi2 = 0; mi2 < 2; ++mi2) {
        const int mi = (rg & 1) * 2 + mi2;
        #pragma unroll
        for (int ni = 0; ni < 8; ++ni) {
          const int col = wc * 128 + ni * 16 + r16;
          #pragma unroll
          for (int r = 0; r < 4; ++r)
            Ls[(mi2 * 16 + g4 * 4 + r) * 516 + col] = acc[mi][ni][r] + bv[ni];
        }
      }
    }
    hard_barrier();
    #pragma unroll
    for (int pass = 0; pass < 4; ++pass) {
      const int rl = pass * 8 + wid;
      const size_t grow = (size_t)(m0 + rg * 32 + rl);
      float v[8];
      short8 s2 = *(const short8*)(an2 + grow * DIMn + l * 8);
      #pragma unroll
      for (int i = 0; i < 8; ++i) v[i] = Ls[rl * 516 + l * 8 + i] + h2f((u16)s2[i]);
      float s = 0.f;
      #pragma unroll
      for (int i = 0; i < 8; ++i) s += v[i];
      s = wredsum(s);
      const float mean = s * (1.0f / 512.0f);
      float q = 0.f;
      #pragma unroll
      for (int i = 0; i < 8; ++i) { const float d = v[i] - mean; q += d * d; }
      q = wredsum(q);
      const float rs = rsqrtf(q * (1.0f / 512.0f) + 1e-6f);
      float4 g0 = *(const float4*)(g + l * 8);
      float4 g1 = *(const float4*)(g + l * 8 + 4);
      float4 e0 = *(const float4*)(be + l * 8);
      float4 e1 = *(const float4*)(be + l * 8 + 4);
      float* o = out + grow * DIMn + l * 8;
      *(float4*)o = make_float4((v[0] - mean) * rs * g0.x + e0.x, (v[1] - mean) * rs * g0.y + e0.y,
                                (v[2] - mean) * rs * g0.z + e0.z, (v[3] - mean) * rs * g0.w + e0.w);
      *(float4*)(o + 4) = make_float4((v[4] - mean) * rs * g1.x + e1.x, (v[5] - mean) * rs * g1.y + e1.y,
                                      (v[6] - mean) * rs * g1.z + e1.z, (v[7] - mean) * rs * g1.w + e1.w);
    }
    hard_barrier();
  }
}

// ---------------- enc-dec attention: per (t,h) a 32x32 batch-attention ----------------
__global__ __launch_bounds__(64) void attn_k(const u16* __restrict__ qe, const float* __restrict__ kin,
                                             const float* __restrict__ vin, u16* __restrict__ wa2) {
  const int t = blockIdx.x >> 3;
  const int h = blockIdx.x & 7;
  const int l = threadIdx.x;
  __shared__ u16 Kq[32 * 80];
  __shared__ u16 Qq[32 * 80];
  __shared__ u16 VT[64 * 48];
  __shared__ u16 Ps[32 * 48];

  const float* kp = kin + (size_t)blockIdx.x * 2048;
  const float* vp = vin + (size_t)blockIdx.x * 2048;
  #pragma unroll
  for (int i = 0; i < 8; ++i) {
    const int fl = i * 256 + l * 4;
    const int r = fl >> 6, c = fl & 63;
    float4 kv = *(const float4*)(kp + fl);
    float4 vv = *(const float4*)(vp + fl);
    *(u32*)&Kq[r * 80 + c]     = pack2h(kv.x, kv.y);
    *(u32*)&Kq[r * 80 + c + 2] = pack2h(kv.z, kv.w);
    VT[(c + 0) * 48 + r] = f2h(vv.x);
    VT[(c + 1) * 48 + r] = f2h(vv.y);
    VT[(c + 2) * 48 + r] = f2h(vv.z);
    VT[(c + 3) * 48 + r] = f2h(vv.w);
  }
  {
    const int qb = l >> 1, hf = l & 1;
    const u16* qp = qe + (size_t)(qb * Tn + t) * DIMn + h * HDn + hf * 32;
    #pragma unroll
    for (int j = 0; j < 4; ++j) {
      short8 d = *(const short8*)(qp + j * 8);
      *(short8*)&Qq[qb * 80 + hf * 32 + j * 8] = d;
    }
  }
  __syncthreads();

  const int r16 = l & 15, g4 = l >> 4;
  f32x4 sacc[2][2] = {};
  #pragma unroll
  for (int kk = 0; kk < 2; ++kk) {
    half8 aQ0 = *(const half8*)&Qq[r16 * 80 + kk * 32 + g4 * 8];
    half8 aQ1 = *(const half8*)&Qq[(16 + r16) * 80 + kk * 32 + g4 * 8];
    half8 bK0 = *(const half8*)&Kq[r16 * 80 + kk * 32 + g4 * 8];
    half8 bK1 = *(const half8*)&Kq[(16 + r16) * 80 + kk * 32 + g4 * 8];
    sacc[0][0] = __builtin_amdgcn_mfma_f32_16x16x32_f16(aQ0, bK0, sacc[0][0], 0, 0, 0);
    sacc[0][1] = __builtin_amdgcn_mfma_f32_16x16x32_f16(aQ0, bK1, sacc[0][1], 0, 0, 0);
    sacc[1][0] = __builtin_amdgcn_mfma_f32_16x16x32_f16(aQ1, bK0, sacc[1][0], 0, 0, 0);
    sacc[1][1] = __builtin_amdgcn_mfma_f32_16x16x32_f16(aQ1, bK1, sacc[1][1], 0, 0, 0);
  }
  #pragma unroll
  for (int m = 0; m < 2; ++m) {
    #pragma unroll
    for (int r = 0; r < 4; ++r) {
      const float a0 = sacc[m][0][r] * 0.125f;
      const float a1 = sacc[m][1][r] * 0.125f;
      float mx = fmaxf(a0, a1);
      #pragma unroll
      for (int d = 1; d < 16; d <<= 1) mx = fmaxf(mx, __shfl_xor(mx, d, 64));
      const float e0 = __expf(a0 - mx), e1 = __expf(a1 - mx);
      float sm = e0 + e1;
      #pragma unroll
      for (int d = 1; d < 16; d <<= 1) sm += __shfl_xor(sm, d, 64);
      const float inv = 1.0f / sm;
      const int rr = m * 16 + g4 * 4 + r;
      Ps[rr * 48 + r16]      = f2h(e0 * inv);
      Ps[rr * 48 + 16 + r16] = f2h(e1 * inv);
    }
  }
  __syncthreads();

  half8 aP0 = *(const half8*)&Ps[r16 * 48 + g4 * 8];
  half8 aP1 = *(const half8*)&Ps[(16 + r16) * 48 + g4 * 8];
  f32x4 oacc[2][4] = {};
  #pragma unroll
  for (int nn = 0; nn < 4; ++nn) {
    half8 bV = *(const half8*)&VT[(nn * 16 + r16) * 48 + g4 * 8];
    oacc[0][nn] = __builtin_amdgcn_mfma_f32_16x16x32_f16(aP0, bV, oacc[0][nn], 0, 0, 0);
    oacc[1][nn] = __builtin_amdgcn_mfma_f32_16x16x32_f16(aP1, bV, oacc[1][nn], 0, 0, 0);
  }
  #pragma unroll
  for (int m = 0; m < 2; ++m) {
    #pragma unroll
    for (int r = 0; r < 4; ++r) {
      const int qb = m * 16 + g4 * 4 + r;
      u16* op = wa2 + (size_t)(qb * Tn + t) * DIMn + h * HDn;
      #pragma unroll
      for (int nn = 0; nn < 4; ++nn)
        op[nn * 16 + r16] = f2h(oacc[m][nn][r]);
    }
  }
}

extern "C" void kernel_launch(void* const* d_in, const int* in_sizes, int n_in,
                              void* d_out, int out_size, void* d_ws, size_t ws_size,
                              hipStream_t stream) {
  (void)in_sizes; (void)n_in; (void)out_size;
  const float* x    = (const float*)d_in[0];
  const float* kin  = (const float*)d_in[1];
  const float* vin  = (const float*)d_in[2];
  const float* Wqkv = (const float*)d_in[3];
  const float* bqkv = (const float*)d_in[4];
  const float* Wsa  = (const float*)d_in[5];
  const float* bsa  = (const float*)d_in[6];
  const float* Wq   = (const float*)d_in[7];
  const float* bq   = (const float*)d_in[8];
  const float* Wed  = (const float*)d_in[9];
  const float* bed  = (const float*)d_in[10];
  const float* g1   = (const float*)d_in[11];
  const float* be1  = (const float*)d_in[12];
  const float* g2   = (const float*)d_in[13];
  const float* be2  = (const float*)d_in[14];
  const float* g3   = (const float*)d_in[15];
  const float* be3  = (const float*)d_in[16];
  const float* W1   = (const float*)d_in[17];
  const float* b1   = (const float*)d_in[18];
  const float* W2   = (const float*)d_in[19];
  const float* b2   = (const float*)d_in[20];

  // ---- workspace layout ----
  char* ws = (char*)d_ws;
  float* xs    = (float*)(ws);
  float* SVp   = (float*)(ws + (2 << 10));
  float* attnc = (float*)(ws + (4 << 10));
  float* part  = (float*)(ws + (6 << 10));
  u16* wqT  = (u16*)(ws + (1 << 20));
  u16* wedT = (u16*)(ws + (1 << 20) + (512 << 10));
  u16* w1T  = (u16*)(ws + (2 << 20));
  u16* w2T  = (u16*)(ws + (4 << 20));
  u16* Abuf = (u16*)(ws + (6 << 20));
  const size_t HOFF = 38ull << 20;
  u16* hmid = (u16*)(ws + HOFF);

  u16* an1  = Abuf;
  u16* wa2  = Abuf;
  u16* an2b = Abuf;
  u16*   qe   = (u16*)d_out;
  u16*   a2bf = (u16*)d_out;
  float* outf = (float*)d_out;

  long long avail = (long long)ws_size - (long long)HOFF;
  int crows = (avail > 0) ? (int)(avail / (HIDn * 2)) : 256;
  crows = (crows / 256) * 256;
  if (crows < 256) crows = 256;
  if (crows > Mn) crows = Mn;

  colsum1<<<256, 256, 0, stream>>>(x, part);
  colsum2<<<2, 256, 0, stream>>>(part, xs);
  sv_k<<<8, 256, 0, stream>>>(xs, Wqkv, bqkv, SVp);
  attnc2_k<<<8, 256, 0, stream>>>(SVp, Wsa, bsa, attnc);

  wtrans<<<dim3(8, 8),  256, 0, stream>>>(Wq,  wqT,  512, 512);
  wtrans<<<dim3(8, 8),  256, 0, stream>>>(Wed, wedT, 512, 512);
  wtrans<<<dim3(32, 8), 256, 0, stream>>>(W1,  w1T,  512, 2048);
  wtrans<<<dim3(8, 32), 256, 0, stream>>>(W2,  w2T,  2048, 512);

  // an1 = LN(x + attn_c)  (f16, Abuf)
  ln_k<0><<<Mn / 4, 256, 0, stream>>>(x, nullptr, attnc, g1, be1, an1);
  // qe = an1 @ Wq + bq  (f16, d_out lower)  -> 256^2 (r15 routing)
  gemm256<false, true><<<256, 512, 0, stream>>>(an1, wqT, bq, qe, nullptr, 512, 512, 2);
  // wa2 (f16, Abuf; an1 dead)
  attn_k<<<Tn * Hn, 64, 0, stream>>>(qe, kin, vin, wa2);
  // attn2 = wa2 @ Wed + bed (f16, d_out lower; qe dead)  -> 256^2
  gemm256<false, true><<<256, 512, 0, stream>>>(wa2, wedT, bed, a2bf, nullptr, 512, 512, 2);
  // an2 = LN(attn2 + x)  (f16, Abuf; wa2 dead)
  ln_k<1><<<Mn / 4, 256, 0, stream>>>(a2bf, x, nullptr, g2, be2, an2b);
  // MLP: hmid = gelu(an2 @ W1 + b1) via 128^2 (r15 routing);
  // out = LN(hmid @ W2 + b2 + an2) fused -- z never hits HBM, LN3 kernel gone.
  for (int r0 = 0; r0 < Mn; r0 += crows) {
    int rc = Mn - r0; if (rc > crows) rc = crows;
    gemm128<true, true><<<16 * (rc / 128), 256, 0, stream>>>(an2b + (size_t)r0 * DIMn, w1T, b1, hmid, nullptr, HIDn, DIMn, 16);
    gemm_mlp2_ln<<<rc / 128, 512, 0, stream>>>(hmid, w2T, b2, an2b + (size_t)r0 * DIMn, g3, be3,
                                               outf + (size_t)r0 * DIMn, HIDn);
  }
}

// Round 18
// 380.915 us; speedup vs baseline: 1.1137x; 1.0488x over previous
//
#include <hip/hip_runtime.h>
#include <hip/hip_bf16.h>
#include <math.h>

#define Bn 32
#define Tn 1024
#define DIMn 512
#define Hn 8
#define HDn 64
#define HIDn 2048
#define Mn 32768

using short8 = __attribute__((ext_vector_type(8))) short;
using half8  = __attribute__((ext_vector_type(8))) _Float16;
using f32x4  = __attribute__((ext_vector_type(4))) float;
typedef unsigned short u16;
typedef unsigned int   u32;

__device__ __forceinline__ u16 f2h(float x) {
  _Float16 h = (_Float16)x;
  return __builtin_bit_cast(u16, h);
}
__device__ __forceinline__ float h2f(u16 u) {
  return (float)__builtin_bit_cast(_Float16, u);
}
__device__ __forceinline__ u32 pack2h(float a, float b) {
  return (u32)f2h(a) | ((u32)f2h(b) << 16);
}
__device__ __forceinline__ void gld16(const void* g, void* l) {
  __builtin_amdgcn_global_load_lds((const __attribute__((address_space(1))) u32*)g,
                                   (__attribute__((address_space(3))) u32*)l, 16, 0, 0);
}
__device__ __forceinline__ float wredsum(float v) {
  #pragma unroll
  for (int d = 1; d < 64; d <<= 1) v += __shfl_xor(v, d, 64);
  return v;
}
__device__ __forceinline__ void hard_barrier() {
  asm volatile("" ::: "memory");
  __builtin_amdgcn_s_barrier();
  asm volatile("" ::: "memory");
}
// Abramowitz-Stegun 7.1.26 erf (|err|<1.5e-7) -> exact GELU at f16 resolution
__device__ __forceinline__ float fast_gelu(float v) {
  const float ax = fabsf(v) * 0.70710678118654752f;
  const float t = 1.0f / (1.0f + 0.3275911f * ax);
  const float p = ((((1.061405429f * t - 1.453152027f) * t) + 1.421413741f) * t - 0.284496736f) * t + 0.254829592f;
  const float y = 1.0f - p * t * __expf(-ax * ax);
  const float erfv = (v >= 0.f) ? y : -y;
  return 0.5f * v * (1.0f + erfv);
}

// ---------------- column sums of x ----------------
__global__ __launch_bounds__(256) void colsum1(const float* __restrict__ x, float* __restrict__ part) {
  const int b = blockIdx.x, t = threadIdx.x;
  const float* p = x + (size_t)b * 128 * DIMn;
  float a0 = 0.f, a1 = 0.f;
  for (int r = 0; r < 128; ++r) {
    a0 += p[r * DIMn + t];
    a1 += p[r * DIMn + t + 256];
  }
  part[b * DIMn + t] = a0;
  part[b * DIMn + t + 256] = a1;
}

__global__ __launch_bounds__(256) void colsum2(const float* __restrict__ part, float* __restrict__ xs) {
  const int c = blockIdx.x * 256 + threadIdx.x;
  float a = 0.f;
  for (int b = 0; b < 256; ++b) a += part[b * DIMn + c];
  xs[c] = a;
}

// SVp[h][f] = XS . Wqkv[:,1024+h*64+f] + 32768*bqkv[...]   (grid 8, 256 thr)
__global__ __launch_bounds__(256) void sv_k(const float* __restrict__ xs, const float* __restrict__ Wqkv,
                                            const float* __restrict__ bqkv, float* __restrict__ SVp) {
  __shared__ float xsh[512];
  __shared__ float red[4][64];
  const int h = blockIdx.x, q = threadIdx.x >> 6, f = threadIdx.x & 63;
  xsh[threadIdx.x] = xs[threadIdx.x];
  xsh[threadIdx.x + 256] = xs[threadIdx.x + 256];
  __syncthreads();
  const int colb = 2 * DIMn + h * HDn + f;
  float acc = 0.f;
  for (int i = q * 128; i < q * 128 + 128; ++i) acc += xsh[i] * Wqkv[(size_t)i * 1536 + colb];
  red[q][f] = acc;
  __syncthreads();
  if (q == 0)
    SVp[h * 64 + f] = red[0][f] + red[1][f] + red[2][f] + red[3][f] + 32768.0f * bqkv[colb];
}

// attnc[j] = bsa[j] + sum_i SV[i&63]*Wsa[i][j]   (grid 8, 256 thr)
__global__ __launch_bounds__(256) void attnc2_k(const float* __restrict__ SVp, const float* __restrict__ Wsa,
                                                const float* __restrict__ bsa, float* __restrict__ attnc) {
  __shared__ float SVs[64];
  __shared__ float red[4][64];
  const int q = threadIdx.x >> 6, jj = threadIdx.x & 63;
  if (threadIdx.x < 64) {
    float s = 0.f;
    #pragma unroll
    for (int h = 0; h < 8; ++h) s += SVp[h * 64 + threadIdx.x];
    SVs[threadIdx.x] = s;
  }
  __syncthreads();
  const int j = blockIdx.x * 64 + jj;
  float acc = 0.f;
  for (int i = q * 128; i < q * 128 + 128; ++i) acc += SVs[i & 63] * Wsa[(size_t)i * DIMn + j];
  red[q][jj] = acc;
  __syncthreads();
  if (q == 0) attnc[j] = red[0][jj] + red[1][jj] + red[2][jj] + red[3][jj] + bsa[j];
}

// ---------------- weight transpose fp32[K][N] -> fp16[N][K] ----------------
__global__ __launch_bounds__(256) void wtrans(const float* __restrict__ W, u16* __restrict__ WT, int K, int N) {
  __shared__ float tile[64][65];
  const int n0 = blockIdx.x * 64, k0 = blockIdx.y * 64;
  const int t = threadIdx.x;
  #pragma unroll
  for (int i = 0; i < 16; ++i) {
    const int fl = i * 256 + t, r = fl >> 6, c = fl & 63;
    tile[r][c] = W[(size_t)(k0 + r) * N + n0 + c];
  }
  __syncthreads();
  #pragma unroll
  for (int i = 0; i < 16; ++i) {
    const int fl = i * 256 + t, r = fl >> 6, c = fl & 63;
    WT[(size_t)(n0 + r) * K + k0 + c] = f2h(tile[c][r]);
  }
}

// ---------------- fused residual LayerNorm, wave per row ----------------
template <int MODE>
__global__ __launch_bounds__(256) void ln_k(const void* __restrict__ Ap, const void* __restrict__ Bp,
                                            const float* __restrict__ cv, const float* __restrict__ g,
                                            const float* __restrict__ be, void* __restrict__ outp) {
  const int row = blockIdx.x * 4 + (threadIdx.x >> 6);
  const int l = threadIdx.x & 63;
  const size_t base = (size_t)row * DIMn + l * 8;
  float v[8];
  if (MODE == 0 || MODE == 2) {
    const float* a = (const float*)Ap + base;
    float4 x0 = *(const float4*)a;
    float4 x1 = *(const float4*)(a + 4);
    v[0] = x0.x; v[1] = x0.y; v[2] = x0.z; v[3] = x0.w;
    v[4] = x1.x; v[5] = x1.y; v[6] = x1.z; v[7] = x1.w;
  } else {
    short8 s = *(const short8*)((const u16*)Ap + base);
    #pragma unroll
    for (int i = 0; i < 8; ++i) v[i] = h2f((u16)s[i]);
  }
  if (MODE == 0) {
    float4 c0 = *(const float4*)(cv + l * 8);
    float4 c1 = *(const float4*)(cv + l * 8 + 4);
    v[0] += c0.x; v[1] += c0.y; v[2] += c0.z; v[3] += c0.w;
    v[4] += c1.x; v[5] += c1.y; v[6] += c1.z; v[7] += c1.w;
  } else if (MODE == 1) {
    const float* b = (const float*)Bp + base;
    float4 x0 = *(const float4*)b;
    float4 x1 = *(const float4*)(b + 4);
    v[0] += x0.x; v[1] += x0.y; v[2] += x0.z; v[3] += x0.w;
    v[4] += x1.x; v[5] += x1.y; v[6] += x1.z; v[7] += x1.w;
  } else {
    short8 s2 = *(const short8*)((const u16*)Bp + base);
    #pragma unroll
    for (int i = 0; i < 8; ++i) v[i] += h2f((u16)s2[i]);
  }
  float s = 0.f;
  #pragma unroll
  for (int i = 0; i < 8; ++i) s += v[i];
  s = wredsum(s);
  const float mean = s * (1.0f / 512.0f);
  float q = 0.f;
  #pragma unroll
  for (int i = 0; i < 8; ++i) { const float d = v[i] - mean; q += d * d; }
  q = wredsum(q);
  const float rs = rsqrtf(q * (1.0f / 512.0f) + 1e-6f);
  float gg[8], bb[8];
  {
    float4 g0 = *(const float4*)(g + l * 8);
    float4 g1 = *(const float4*)(g + l * 8 + 4);
    float4 b0 = *(const float4*)(be + l * 8);
    float4 b1 = *(const float4*)(be + l * 8 + 4);
    gg[0] = g0.x; gg[1] = g0.y; gg[2] = g0.z; gg[3] = g0.w;
    gg[4] = g1.x; gg[5] = g1.y; gg[6] = g1.z; gg[7] = g1.w;
    bb[0] = b0.x; bb[1] = b0.y; bb[2] = b0.z; bb[3] = b0.w;
    bb[4] = b1.x; bb[5] = b1.y; bb[6] = b1.z; bb[7] = b1.w;
  }
  float y[8];
  #pragma unroll
  for (int i = 0; i < 8; ++i) y[i] = (v[i] - mean) * rs * gg[i] + bb[i];
  if (MODE == 2) {
    float* o = (float*)outp + base;
    *(float4*)o = make_float4(y[0], y[1], y[2], y[3]);
    *(float4*)(o + 4) = make_float4(y[4], y[5], y[6], y[7]);
  } else {
    short8 o;
    #pragma unroll
    for (int i = 0; i < 8; ++i) o[i] = (short)f2h(y[i]);
    *(short8*)((u16*)outp + base) = o;
  }
}

// ---------------- GEMM kernel A: 128x128 tile (r13/r15-proven: 155us on MLP1) ----------------
#define CPAD 132
template <bool GELU, bool OBF>
__global__ __launch_bounds__(256) void gemm128(const u16* __restrict__ A, const u16* __restrict__ BT,
                                               const float* __restrict__ bias, u16* __restrict__ OB,
                                               float* __restrict__ OF, int Ni, int Ki, int gridX) {
  __shared__ u16 smem[3 * 8192];
  const int tid = threadIdx.x;
  const int l = tid & 63, w = tid >> 6, wr = w >> 1, wc = w & 1;

  int wg = blockIdx.x;
  const int nwg = gridDim.x;
  if ((nwg & 7) == 0) {
    const int q = nwg >> 3;
    wg = (wg & 7) * q + (wg >> 3);
  }
  const int bx = wg % gridX, by = wg / gridX;
  const int m0 = by * 128, n0 = bx * 128;
  const int r16 = l & 15, g4 = l >> 4;

  const int schunk = (tid & 3) ^ ((tid >> 2) & 3);
  const u16* ga = A + (size_t)(m0 + (tid >> 2)) * (size_t)Ki + schunk * 8;
  const u16* gb = BT + (size_t)(n0 + (tid >> 2)) * (size_t)Ki + schunk * 8;
  const int ldst = tid * 8;

  const int g4s = g4 ^ (r16 & 3);
  int aoff[4], boff[4];
  #pragma unroll
  for (int i = 0; i < 4; ++i) {
    aoff[i] = (wr * 64 + i * 16 + r16) * 32 + g4s * 8;
    boff[i] = 4096 + (wc * 64 + i * 16 + r16) * 32 + g4s * 8;
  }
  f32x4 acc[4][4] = {};

  const int nt = Ki >> 5;
  auto STAGE = [&](int t, int b) {
    u16* base = smem + b * 8192;
    const int kk = t * 32;
    gld16(ga + kk, &base[ldst]);
    gld16(ga + kk + (size_t)64 * Ki, &base[ldst + 2048]);
    gld16(gb + kk, &base[4096 + ldst]);
    gld16(gb + kk + (size_t)64 * Ki, &base[4096 + ldst + 2048]);
  };

  STAGE(0, 0);
  STAGE(1, 1);
  int b0 = 0, b1 = 1, b2 = 2;
  for (int t = 0; t < nt; ++t) {
    if (t < nt - 1) asm volatile("s_waitcnt vmcnt(4)" ::: "memory");
    else            asm volatile("s_waitcnt vmcnt(0)" ::: "memory");
    hard_barrier();
    if (t + 2 < nt) STAGE(t + 2, b2);
    const u16* base = smem + b0 * 8192;
    half8 af[4], bf[4];
    #pragma unroll
    for (int i = 0; i < 4; ++i) af[i] = *(const half8*)&base[aoff[i]];
    #pragma unroll
    for (int i = 0; i < 4; ++i) bf[i] = *(const half8*)&base[boff[i]];
    #pragma unroll
    for (int mi = 0; mi < 4; ++mi)
      #pragma unroll
      for (int ni = 0; ni < 4; ++ni)
        acc[mi][ni] = __builtin_amdgcn_mfma_f32_16x16x32_f16(af[mi], bf[ni], acc[mi][ni], 0, 0, 0);
    hard_barrier();
    const int tb = b0; b0 = b1; b1 = b2; b2 = tb;
  }

  if (OBF) {
    u16* Cs = smem;
    #pragma unroll
    for (int ni = 0; ni < 4; ++ni) {
      const int col = wc * 64 + ni * 16 + r16;
      const float bv = bias[n0 + col];
      #pragma unroll
      for (int mi = 0; mi < 4; ++mi) {
        const int rowb = wr * 64 + mi * 16 + g4 * 4;
        #pragma unroll
        for (int r = 0; r < 4; ++r) {
          float v = acc[mi][ni][r] + bv;
          if (GELU) v = fast_gelu(v);
          Cs[(rowb + r) * CPAD + col] = f2h(v);
        }
      }
    }
    hard_barrier();
    const int rr = tid >> 4;
    const int c0 = (tid & 15) * 8;
    #pragma unroll
    for (int j = 0; j < 8; ++j) {
      const int row = rr + j * 16;
      *(short8*)(OB + (size_t)(m0 + row) * Ni + n0 + c0) = *(const short8*)&Cs[row * CPAD + c0];
    }
  } else {
    #pragma unroll
    for (int ni = 0; ni < 4; ++ni) {
      const int col = n0 + wc * 64 + ni * 16 + r16;
      const float bv = bias[col];
      #pragma unroll
      for (int mi = 0; mi < 4; ++mi) {
        const int rowb = m0 + wr * 64 + mi * 16 + g4 * 4;
        #pragma unroll
        for (int r = 0; r < 4; ++r) {
          float v = acc[mi][ni][r] + bv;
          if (GELU) v = fast_gelu(v);
          OF[(size_t)(rowb + r) * Ni + col] = v;
        }
      }
    }
  }
}

// ---------------- GEMM kernel B: 256x256 tile (r14/r15-proven for N=512 shapes) ----------------
#define CROW 272
template <bool GELU, bool OBF>
__global__ __launch_bounds__(512) void gemm256(const u16* __restrict__ A, const u16* __restrict__ BT,
                                               const float* __restrict__ bias, u16* __restrict__ OB,
                                               float* __restrict__ OF, int Ni, int Ki, int gridX) {
  __shared__ u16 smem[49152];
  const int tid = threadIdx.x;
  const int l = tid & 63, wid = tid >> 6, wr = wid >> 2, wc = wid & 3;

  int wg = blockIdx.x;
  const int nwg = gridDim.x;
  if ((nwg & 7) == 0) {
    const int q = nwg >> 3;
    wg = (wg & 7) * q + (wg >> 3);
  }
  const int bx = wg % gridX, by = wg / gridX;
  const int m0 = by * 256, n0 = bx * 256;
  const int r16 = l & 15, g4 = l >> 4;

  const int srow = tid >> 2, schunk = (tid & 3) * 8;
  const u16* gaA = A  + (size_t)(m0 + srow) * (size_t)Ki + schunk;
  const u16* gaB = BT + (size_t)(n0 + srow) * (size_t)Ki + schunk;
  const size_t rowskip = (size_t)128 * (size_t)Ki;
  const int ldst = tid * 8;

  int aoff[8], boff[4];
  #pragma unroll
  for (int mi = 0; mi < 8; ++mi) aoff[mi] = (wr * 128 + mi * 16 + r16) * 32 + g4 * 8;
  #pragma unroll
  for (int ni = 0; ni < 4; ++ni) boff[ni] = 8192 + (wc * 64 + ni * 16 + r16) * 32 + g4 * 8;

  f32x4 acc[8][4] = {};
  const int nt = Ki >> 5;

  auto STAGE = [&](int t, int b) {
    u16* base = smem + b * 16384;
    const int kk = t * 32;
    gld16(gaA + kk, &base[ldst]);
    gld16(gaA + kk + rowskip, &base[ldst + 4096]);
    gld16(gaB + kk, &base[8192 + ldst]);
    gld16(gaB + kk + rowskip, &base[8192 + ldst + 4096]);
  };

  STAGE(0, 0);
  STAGE(1, 1);
  int b0 = 0, b1 = 1, b2 = 2;
  for (int t = 0; t < nt; ++t) {
    if (t < nt - 1) asm volatile("s_waitcnt vmcnt(4)" ::: "memory");
    else            asm volatile("s_waitcnt vmcnt(0)" ::: "memory");
    hard_barrier();
    if (t + 2 < nt) STAGE(t + 2, b2);
    const u16* base = smem + b0 * 16384;
    half8 bf[4];
    #pragma unroll
    for (int ni = 0; ni < 4; ++ni) bf[ni] = *(const half8*)&base[boff[ni]];
    #pragma unroll
    for (int mi = 0; mi < 8; ++mi) {
      half8 af = *(const half8*)&base[aoff[mi]];
      #pragma unroll
      for (int ni = 0; ni < 4; ++ni)
        acc[mi][ni] = __builtin_amdgcn_mfma_f32_16x16x32_f16(af, bf[ni], acc[mi][ni], 0, 0, 0);
    }
    hard_barrier();
    const int tb = b0; b0 = b1; b1 = b2; b2 = tb;
  }

  if (OBF) {
    u16* Cs = smem;
    float bv[4];
    #pragma unroll
    for (int ni = 0; ni < 4; ++ni) bv[ni] = bias[n0 + wc * 64 + ni * 16 + r16];
    #pragma unroll
    for (int p = 0; p < 2; ++p) {
      #pragma unroll
      for (int mi4 = 0; mi4 < 4; ++mi4) {
        const int mi = p * 4 + mi4;
        #pragma unroll
        for (int ni = 0; ni < 4; ++ni) {
          const int colL = wc * 64 + ni * 16 + r16;
          #pragma unroll
          for (int r = 0; r < 4; ++r) {
            float v = acc[mi][ni][r] + bv[ni];
            if (GELU) v = fast_gelu(v);
            Cs[wr * (64 * CROW) + (mi4 * 16 + g4 * 4 + r) * CROW + colL] = f2h(v);
          }
        }
      }
      hard_barrier();
      #pragma unroll
      for (int j = 0; j < 8; ++j) {
        const int s = tid + j * 512;
        const int wrS = s >> 11;
        const int rowL = (s & 2047) >> 5;
        const int c8 = s & 31;
        *(short8*)(OB + (size_t)(m0 + wrS * 128 + p * 64 + rowL) * Ni + n0 + c8 * 8) =
            *(const short8*)&Cs[wrS * (64 * CROW) + rowL * CROW + c8 * 8];
      }
      if (p == 0) hard_barrier();
    }
  } else {
    #pragma unroll
    for (int ni = 0; ni < 4; ++ni) {
      const int col = n0 + wc * 64 + ni * 16 + r16;
      const float bvv = bias[col];
      #pragma unroll
      for (int mi = 0; mi < 8; ++mi) {
        const int rowb = m0 + wr * 128 + mi * 16 + g4 * 4;
        #pragma unroll
        for (int r = 0; r < 4; ++r) {
          float v = acc[mi][ni][r] + bvv;
          if (GELU) v = fast_gelu(v);
          OF[(size_t)(rowb + r) * Ni + col] = v;
        }
      }
    }
  }
}

// ------- fused GEMM (128 rows x FULL 512 cols) + residual LayerNorm epilogue -------
// RESF32: residual is f32 (x) else f16; OUTF32: output f32 (d_out) else f16.
// Used for: attn2+LN2 (RESF32=1, OUTF32=0, A=wa2 -> out=an2b, row-disjoint in-place safe)
// and MLP2+LN3 (RESF32=0, OUTF32=1). r17-proven skeleton: 3-buf lead-2 vmcnt(5), 120KB LDS.
template <bool RESF32, bool OUTF32>
__global__ __launch_bounds__(512) void gemm_fln(const u16* __restrict__ A, const u16* __restrict__ BT,
                                                const float* __restrict__ bias, const void* __restrict__ resid,
                                                const float* __restrict__ g, const float* __restrict__ be,
                                                void* __restrict__ out, int Ki) {
  __shared__ u16 smem[61440];   // 120KB: 3 bufs x (A[128][32]=4096 | B[512][32]=16384) u16
  const int tid = threadIdx.x;
  const int l = tid & 63, wid = tid >> 6, wr = wid >> 2, wc = wid & 3;
  const int m0 = blockIdx.x * 128;
  const int r16 = l & 15, g4 = l >> 4;

  const u16* gA = A  + (size_t)(m0 + (tid >> 2)) * (size_t)Ki + (tid & 3) * 8;
  const u16* gB = BT + (size_t)(tid >> 2) * (size_t)Ki + (tid & 3) * 8;
  const size_t r128 = (size_t)128 * Ki;

  int aoff[4], boff[8];
  #pragma unroll
  for (int mi = 0; mi < 4; ++mi) aoff[mi] = (wr * 64 + mi * 16 + r16) * 32 + g4 * 8;
  #pragma unroll
  for (int ni = 0; ni < 8; ++ni) boff[ni] = 4096 + (wc * 128 + ni * 16 + r16) * 32 + g4 * 8;

  f32x4 acc[4][8] = {};
  const int nt = Ki >> 5;

  auto STAGE = [&](int t, int b) {
    u16* base = smem + b * 20480;
    const int kk = t * 32;
    gld16(gA + kk, &base[tid * 8]);
    #pragma unroll
    for (int j = 0; j < 4; ++j)
      gld16(gB + kk + (size_t)j * r128, &base[4096 + tid * 8 + j * 4096]);
  };

  STAGE(0, 0);
  STAGE(1, 1);
  int b0 = 0, b1 = 1, b2 = 2;
  for (int t = 0; t < nt; ++t) {
    if (t < nt - 1) asm volatile("s_waitcnt vmcnt(5)" ::: "memory");
    else            asm volatile("s_waitcnt vmcnt(0)" ::: "memory");
    hard_barrier();
    if (t + 2 < nt) STAGE(t + 2, b2);
    const u16* base = smem + b0 * 20480;
    half8 af[4];
    #pragma unroll
    for (int mi = 0; mi < 4; ++mi) af[mi] = *(const half8*)&base[aoff[mi]];
    #pragma unroll
    for (int ni = 0; ni < 8; ++ni) {
      half8 bf = *(const half8*)&base[boff[ni]];
      #pragma unroll
      for (int mi = 0; mi < 4; ++mi)
        acc[mi][ni] = __builtin_amdgcn_mfma_f32_16x16x32_f16(af[mi], bf, acc[mi][ni], 0, 0, 0);
    }
    hard_barrier();
    const int tb = b0; b0 = b1; b1 = b2; b2 = tb;
  }

  // epilogue: 4 groups of 32 rows; stage z=acc+bias f32 in LDS, then wave-per-row LN
  float* Ls = (float*)smem;   // [32][516] f32 = 66KB
  float bv[8];
  #pragma unroll
  for (int ni = 0; ni < 8; ++ni) bv[ni] = bias[wc * 128 + ni * 16 + r16];
  #pragma unroll
  for (int rg = 0; rg < 4; ++rg) {
    if (wr == (rg >> 1)) {
      #pragma unroll
      for (int mi2 = 0; mi2 < 2; ++mi2) {
        const int mi = (rg & 1) * 2 + mi2;
        #pragma unroll
        for (int ni = 0; ni < 8; ++ni) {
          const int col = wc * 128 + ni * 16 + r16;
          #pragma unroll
          for (int r = 0; r < 4; ++r)
            Ls[(mi2 * 16 + g4 * 4 + r) * 516 + col] = acc[mi][ni][r] + bv[ni];
        }
      }
    }
    hard_barrier();
    #pragma unroll
    for (int pass = 0; pass < 4; ++pass) {
      const int rl = pass * 8 + wid;
      const size_t grow = (size_t)(m0 + rg * 32 + rl);
      float v[8];
      if (RESF32) {
        const float* rp = (const float*)resid + grow * DIMn + l * 8;
        float4 x0 = *(const float4*)rp;
        float4 x1 = *(const float4*)(rp + 4);
        v[0] = Ls[rl * 516 + l * 8 + 0] + x0.x; v[1] = Ls[rl * 516 + l * 8 + 1] + x0.y;
        v[2] = Ls[rl * 516 + l * 8 + 2] + x0.z; v[3] = Ls[rl * 516 + l * 8 + 3] + x0.w;
        v[4] = Ls[rl * 516 + l * 8 + 4] + x1.x; v[5] = Ls[rl * 516 + l * 8 + 5] + x1.y;
        v[6] = Ls[rl * 516 + l * 8 + 6] + x1.z; v[7] = Ls[rl * 516 + l * 8 + 7] + x1.w;
      } else {
        short8 s2 = *(const short8*)((const u16*)resid + grow * DIMn + l * 8);
        #pragma unroll
        for (int i = 0; i < 8; ++i) v[i] = Ls[rl * 516 + l * 8 + i] + h2f((u16)s2[i]);
      }
      float s = 0.f;
      #pragma unroll
      for (int i = 0; i < 8; ++i) s += v[i];
      s = wredsum(s);
      const float mean = s * (1.0f / 512.0f);
      float q = 0.f;
      #pragma unroll
      for (int i = 0; i < 8; ++i) { const float d = v[i] - mean; q += d * d; }
      q = wredsum(q);
      const float rs = rsqrtf(q * (1.0f / 512.0f) + 1e-6f);
      float4 g0 = *(const float4*)(g + l * 8);
      float4 g1 = *(const float4*)(g + l * 8 + 4);
      float4 e0 = *(const float4*)(be + l * 8);
      float4 e1 = *(const float4*)(be + l * 8 + 4);
      float y[8];
      y[0] = (v[0] - mean) * rs * g0.x + e0.x; y[1] = (v[1] - mean) * rs * g0.y + e0.y;
      y[2] = (v[2] - mean) * rs * g0.z + e0.z; y[3] = (v[3] - mean) * rs * g0.w + e0.w;
      y[4] = (v[4] - mean) * rs * g1.x + e1.x; y[5] = (v[5] - mean) * rs * g1.y + e1.y;
      y[6] = (v[6] - mean) * rs * g1.z + e1.z; y[7] = (v[7] - mean) * rs * g1.w + e1.w;
      if (OUTF32) {
        float* o = (float*)out + grow * DIMn + l * 8;
        *(float4*)o = make_float4(y[0], y[1], y[2], y[3]);
        *(float4*)(o + 4) = make_float4(y[4], y[5], y[6], y[7]);
      } else {
        short8 o;
        #pragma unroll
        for (int i = 0; i < 8; ++i) o[i] = (short)f2h(y[i]);
        *(short8*)((u16*)out + grow * DIMn + l * 8) = o;
      }
    }
    hard_barrier();
  }
}

// ---------------- enc-dec attention: per (t,h) a 32x32 batch-attention ----------------
__global__ __launch_bounds__(64) void attn_k(const u16* __restrict__ qe, const float* __restrict__ kin,
                                             const float* __restrict__ vin, u16* __restrict__ wa2) {
  const int t = blockIdx.x >> 3;
  const int h = blockIdx.x & 7;
  const int l = threadIdx.x;
  __shared__ u16 Kq[32 * 80];
  __shared__ u16 Qq[32 * 80];
  __shared__ u16 VT[64 * 48];
  __shared__ u16 Ps[32 * 48];

  const float* kp = kin + (size_t)blockIdx.x * 2048;
  const float* vp = vin + (size_t)blockIdx.x * 2048;
  #pragma unroll
  for (int i = 0; i < 8; ++i) {
    const int fl = i * 256 + l * 4;
    const int r = fl >> 6, c = fl & 63;
    float4 kv = *(const float4*)(kp + fl);
    float4 vv = *(const float4*)(vp + fl);
    *(u32*)&Kq[r * 80 + c]     = pack2h(kv.x, kv.y);
    *(u32*)&Kq[r * 80 + c + 2] = pack2h(kv.z, kv.w);
    VT[(c + 0) * 48 + r] = f2h(vv.x);
    VT[(c + 1) * 48 + r] = f2h(vv.y);
    VT[(c + 2) * 48 + r] = f2h(vv.z);
    VT[(c + 3) * 48 + r] = f2h(vv.w);
  }
  {
    const int qb = l >> 1, hf = l & 1;
    const u16* qp = qe + (size_t)(qb * Tn + t) * DIMn + h * HDn + hf * 32;
    #pragma unroll
    for (int j = 0; j < 4; ++j) {
      short8 d = *(const short8*)(qp + j * 8);
      *(short8*)&Qq[qb * 80 + hf * 32 + j * 8] = d;
    }
  }
  __syncthreads();

  const int r16 = l & 15, g4 = l >> 4;
  f32x4 sacc[2][2] = {};
  #pragma unroll
  for (int kk = 0; kk < 2; ++kk) {
    half8 aQ0 = *(const half8*)&Qq[r16 * 80 + kk * 32 + g4 * 8];
    half8 aQ1 = *(const half8*)&Qq[(16 + r16) * 80 + kk * 32 + g4 * 8];
    half8 bK0 = *(const half8*)&Kq[r16 * 80 + kk * 32 + g4 * 8];
    half8 bK1 = *(const half8*)&Kq[(16 + r16) * 80 + kk * 32 + g4 * 8];
    sacc[0][0] = __builtin_amdgcn_mfma_f32_16x16x32_f16(aQ0, bK0, sacc[0][0], 0, 0, 0);
    sacc[0][1] = __builtin_amdgcn_mfma_f32_16x16x32_f16(aQ0, bK1, sacc[0][1], 0, 0, 0);
    sacc[1][0] = __builtin_amdgcn_mfma_f32_16x16x32_f16(aQ1, bK0, sacc[1][0], 0, 0, 0);
    sacc[1][1] = __builtin_amdgcn_mfma_f32_16x16x32_f16(aQ1, bK1, sacc[1][1], 0, 0, 0);
  }
  #pragma unroll
  for (int m = 0; m < 2; ++m) {
    #pragma unroll
    for (int r = 0; r < 4; ++r) {
      const float a0 = sacc[m][0][r] * 0.125f;
      const float a1 = sacc[m][1][r] * 0.125f;
      float mx = fmaxf(a0, a1);
      #pragma unroll
      for (int d = 1; d < 16; d <<= 1) mx = fmaxf(mx, __shfl_xor(mx, d, 64));
      const float e0 = __expf(a0 - mx), e1 = __expf(a1 - mx);
      float sm = e0 + e1;
      #pragma unroll
      for (int d = 1; d < 16; d <<= 1) sm += __shfl_xor(sm, d, 64);
      const float inv = 1.0f / sm;
      const int rr = m * 16 + g4 * 4 + r;
      Ps[rr * 48 + r16]      = f2h(e0 * inv);
      Ps[rr * 48 + 16 + r16] = f2h(e1 * inv);
    }
  }
  __syncthreads();

  half8 aP0 = *(const half8*)&Ps[r16 * 48 + g4 * 8];
  half8 aP1 = *(const half8*)&Ps[(16 + r16) * 48 + g4 * 8];
  f32x4 oacc[2][4] = {};
  #pragma unroll
  for (int nn = 0; nn < 4; ++nn) {
    half8 bV = *(const half8*)&VT[(nn * 16 + r16) * 48 + g4 * 8];
    oacc[0][nn] = __builtin_amdgcn_mfma_f32_16x16x32_f16(aP0, bV, oacc[0][nn], 0, 0, 0);
    oacc[1][nn] = __builtin_amdgcn_mfma_f32_16x16x32_f16(aP1, bV, oacc[1][nn], 0, 0, 0);
  }
  #pragma unroll
  for (int m = 0; m < 2; ++m) {
    #pragma unroll
    for (int r = 0; r < 4; ++r) {
      const int qb = m * 16 + g4 * 4 + r;
      u16* op = wa2 + (size_t)(qb * Tn + t) * DIMn + h * HDn;
      #pragma unroll
      for (int nn = 0; nn < 4; ++nn)
        op[nn * 16 + r16] = f2h(oacc[m][nn][r]);
    }
  }
}

extern "C" void kernel_launch(void* const* d_in, const int* in_sizes, int n_in,
                              void* d_out, int out_size, void* d_ws, size_t ws_size,
                              hipStream_t stream) {
  (void)in_sizes; (void)n_in; (void)out_size;
  const float* x    = (const float*)d_in[0];
  const float* kin  = (const float*)d_in[1];
  const float* vin  = (const float*)d_in[2];
  const float* Wqkv = (const float*)d_in[3];
  const float* bqkv = (const float*)d_in[4];
  const float* Wsa  = (const float*)d_in[5];
  const float* bsa  = (const float*)d_in[6];
  const float* Wq   = (const float*)d_in[7];
  const float* bq   = (const float*)d_in[8];
  const float* Wed  = (const float*)d_in[9];
  const float* bed  = (const float*)d_in[10];
  const float* g1   = (const float*)d_in[11];
  const float* be1  = (const float*)d_in[12];
  const float* g2   = (const float*)d_in[13];
  const float* be2  = (const float*)d_in[14];
  const float* g3   = (const float*)d_in[15];
  const float* be3  = (const float*)d_in[16];
  const float* W1   = (const float*)d_in[17];
  const float* b1   = (const float*)d_in[18];
  const float* W2   = (const float*)d_in[19];
  const float* b2   = (const float*)d_in[20];

  // ---- workspace layout ----
  char* ws = (char*)d_ws;
  float* xs    = (float*)(ws);
  float* SVp   = (float*)(ws + (2 << 10));
  float* attnc = (float*)(ws + (4 << 10));
  float* part  = (float*)(ws + (6 << 10));
  u16* wqT  = (u16*)(ws + (1 << 20));
  u16* wedT = (u16*)(ws + (1 << 20) + (512 << 10));
  u16* w1T  = (u16*)(ws + (2 << 20));
  u16* w2T  = (u16*)(ws + (4 << 20));
  u16* Abuf = (u16*)(ws + (6 << 20));
  const size_t HOFF = 38ull << 20;
  u16* hmid = (u16*)(ws + HOFF);

  u16* an1  = Abuf;
  u16* wa2  = Abuf;
  u16* an2b = Abuf;   // gemm_fln<attn2> writes an2b over wa2 row-disjoint (safe)
  u16*   qe   = (u16*)d_out;
  float* outf = (float*)d_out;

  long long avail = (long long)ws_size - (long long)HOFF;
  int crows = (avail > 0) ? (int)(avail / (HIDn * 2)) : 256;
  crows = (crows / 256) * 256;
  if (crows < 256) crows = 256;
  if (crows > Mn) crows = Mn;

  colsum1<<<256, 256, 0, stream>>>(x, part);
  colsum2<<<2, 256, 0, stream>>>(part, xs);
  sv_k<<<8, 256, 0, stream>>>(xs, Wqkv, bqkv, SVp);
  attnc2_k<<<8, 256, 0, stream>>>(SVp, Wsa, bsa, attnc);

  wtrans<<<dim3(8, 8),  256, 0, stream>>>(Wq,  wqT,  512, 512);
  wtrans<<<dim3(8, 8),  256, 0, stream>>>(Wed, wedT, 512, 512);
  wtrans<<<dim3(32, 8), 256, 0, stream>>>(W1,  w1T,  512, 2048);
  wtrans<<<dim3(8, 32), 256, 0, stream>>>(W2,  w2T,  2048, 512);

  // an1 = LN(x + attn_c)  (f16, Abuf)
  ln_k<0><<<Mn / 4, 256, 0, stream>>>(x, nullptr, attnc, g1, be1, an1);
  // qe = an1 @ Wq + bq  (f16, d_out lower)
  gemm256<false, true><<<256, 512, 0, stream>>>(an1, wqT, bq, qe, nullptr, 512, 512, 2);
  // wa2 (f16, Abuf; an1 dead)
  attn_k<<<Tn * Hn, 64, 0, stream>>>(qe, kin, vin, wa2);
  // an2 = LN(wa2 @ Wed + bed + x)  FUSED (f16 -> Abuf in-place row-disjoint; LN2 kernel gone)
  gemm_fln<true, false><<<Mn / 128, 512, 0, stream>>>(wa2, wedT, bed, x, g2, be2, an2b, 512);
  // MLP: hmid = gelu(an2 @ W1 + b1) via 128^2; out = LN(hmid @ W2 + b2 + an2) FUSED
  for (int r0 = 0; r0 < Mn; r0 += crows) {
    int rc = Mn - r0; if (rc > crows) rc = crows;
    gemm128<true, true><<<16 * (rc / 128), 256, 0, stream>>>(an2b + (size_t)r0 * DIMn, w1T, b1, hmid, nullptr, HIDn, DIMn, 16);
    gemm_fln<false, true><<<rc / 128, 512, 0, stream>>>(hmid, w2T, b2, an2b + (size_t)r0 * DIMn, g3, be3,
                                                        outf + (size_t)r0 * DIMn, HIDn);
  }
}